// Round 8
// baseline (173.101 us; speedup 1.0000x reference)
//
#include <hip/hip_runtime.h>
#include <hip/hip_bf16.h>
#include <math.h>

#define Bn 8
#define Ln 512
#define Dn 768
#define NHn 12
#define DHn 64
#define K1n 20
#define K2n 20

// workspace layout (bytes)
#define WS_ACC    0          // double acc[8]: [0]=pair_num [1]=trip_num [2]=trip_cnt; bytes 48..51 = done-counter
#define WS_GSCORE 64         // float g_score[8*512]
#define WS_LOCR   16448      // float loc_rows[8*20*512] (320 KB)
#define WS_GTOP   344128     // int g_top[8*20]
#define WS_SBF    357568     // ushort sbf[8*12*512*64] bf16 head-major
#define WS_TBF    6649024    // ushort tbf[...] (ends 12940480)
#define WS_ZERO_BYTES 344128 // acc + counter + g_score + loc_rows

typedef __attribute__((ext_vector_type(8))) short bf16x8;
typedef __attribute__((ext_vector_type(4))) float f32x4;

__device__ inline unsigned short f2bf(float x) {
  __hip_bfloat16 h = __float2bfloat16(x);
  return *reinterpret_cast<unsigned short*>(&h);
}
__device__ inline float bf2f(unsigned short u) {
  return __uint_as_float(((unsigned int)u) << 16);
}

// ---------------------------------------------------------------------------
// Prep: fp32 [b][row][h*64+k] -> bf16 head-major [b][h][row][k]
// ---------------------------------------------------------------------------
__global__ __launch_bounds__(256) void prep_bf16_kernel(
    const float* __restrict__ s, const float* __restrict__ t,
    unsigned short* __restrict__ sbf, unsigned short* __restrict__ tbf) {
  int gid = blockIdx.x * 256 + threadIdx.x;
  int f = gid * 4;
  int col = f % Dn;
  int rb = f / Dn;
  int row = rb & (Ln - 1);
  int b = rb >> 9;
  int h = col >> 6;
  int k = col & 63;
  size_t dst = (((size_t)(b * NHn + h) * Ln + row) * DHn + k);
  float4 vs = *(const float4*)(s + f);
  float4 vt = *(const float4*)(t + f);
  ushort4 us, ut;
  us.x = f2bf(vs.x); us.y = f2bf(vs.y); us.z = f2bf(vs.z); us.w = f2bf(vs.w);
  ut.x = f2bf(vt.x); ut.y = f2bf(vt.y); ut.z = f2bf(vt.z); ut.w = f2bf(vt.w);
  *(ushort4*)(sbf + dst) = us;
  *(ushort4*)(tbf + dst) = ut;
}

// ---------------------------------------------------------------------------
// Kernel A (two-pass recompute, column-split): one block per (b, h, 32-row
// tile). Wave (wr,wc) owns 16 rows x 256 cols -> grid 1536 = 6 blocks/CU
// (~75% occupancy vs round 6's 3 blocks/CU). Row sums via one 2-way LDS
// exchange. Pass 2 recomputes t-scores+exp (bf16 MFMA deterministic).
// ---------------------------------------------------------------------------
__global__ __launch_bounds__(256) void pairA_kernel(
    const unsigned short* __restrict__ sbf, const unsigned short* __restrict__ tbf,
    const float* __restrict__ mask, float* __restrict__ g_score,
    double* __restrict__ acc) {
  const int b = blockIdx.x & 7;
  const int r = blockIdx.x >> 3;          // 0..191
  const int it = r / NHn;                 // 0..15
  const int h = r - it * NHn;             // 0..11
  const int tid = threadIdx.x;
  const int w = tid >> 6;
  const int wr = w >> 1;                  // row strip 0/1
  const int wc = w & 1;                   // col half 0/1
  const int lane = tid & 63;
  const int lr = lane & 15, lg = lane >> 4;

  __shared__ float Mcol[Ln];
  __shared__ float gcol[Ln];
  __shared__ float redsum[2][2][16];      // [wc][wr][row]
  __shared__ float wred[4];

  for (int j = tid; j < Ln; j += 256) {
    Mcol[j] = mask[b * Ln + j];
    gcol[j] = 0.0f;
  }
  __syncthreads();

  const size_t hb = (size_t)(b * NHn + h) * Ln;
  const int rw = it * 32 + wr * 16;
  const unsigned short* pas = sbf + (hb + rw + lr) * DHn + lg * 8;
  const unsigned short* pat = tbf + (hb + rw + lr) * DHn + lg * 8;
  bf16x8 sa0 = *(const bf16x8*)pas;
  bf16x8 sa1 = *(const bf16x8*)(pas + 32);
  bf16x8 ta0 = *(const bf16x8*)pat;
  bf16x8 ta1 = *(const bf16x8*)(pat + 32);
  float mrow[4];
  #pragma unroll
  for (int q = 0; q < 4; ++q) mrow[q] = Mcol[rw + lg * 4 + q];

  const f32x4 zero4 = {0.0f, 0.0f, 0.0f, 0.0f};
  const int cbase = wc * 256;
  float lpair = 0.0f;
  float rsum[4] = {0.0f, 0.0f, 0.0f, 0.0f};

  // ---- pass 1: diff^2 + unnormalized row sums over this wave's 256 cols ----
  for (int ct = 0; ct < 16; ++ct) {
    const int j0 = cbase + ct * 16;
    const unsigned short* pbs = sbf + (hb + j0 + lr) * DHn + lg * 8;
    const unsigned short* pbt = tbf + (hb + j0 + lr) * DHn + lg * 8;
    bf16x8 sb0 = *(const bf16x8*)pbs;
    bf16x8 sb1 = *(const bf16x8*)(pbs + 32);
    bf16x8 tb0 = *(const bf16x8*)pbt;
    bf16x8 tb1 = *(const bf16x8*)(pbt + 32);
    f32x4 sacc = __builtin_amdgcn_mfma_f32_16x16x32_bf16(sa0, sb0, zero4, 0, 0, 0);
    sacc = __builtin_amdgcn_mfma_f32_16x16x32_bf16(sa1, sb1, sacc, 0, 0, 0);
    f32x4 tacc = __builtin_amdgcn_mfma_f32_16x16x32_bf16(ta0, tb0, zero4, 0, 0, 0);
    tacc = __builtin_amdgcn_mfma_f32_16x16x32_bf16(ta1, tb1, tacc, 0, 0, 0);
    const float mj = Mcol[j0 + lr];
    #pragma unroll
    for (int q = 0; q < 4; ++q) {
      const float mm = mrow[q] * mj;
      const float ss = sacc[q] * 0.125f * mm;
      const float st = tacc[q] * 0.125f * mm;
      const float d = ss - st;
      lpair += d * d;
      rsum[q] += __expf(st + (1.0f - mm) * (-10000.0f));
    }
  }

  // wave-local partial row sums -> LDS exchange across col halves
  #pragma unroll
  for (int o = 1; o < 16; o <<= 1) {
    #pragma unroll
    for (int q = 0; q < 4; ++q) rsum[q] += __shfl_xor(rsum[q], o, 64);
  }
  if (lr == 0) {
    #pragma unroll
    for (int q = 0; q < 4; ++q) redsum[wc][wr][lg * 4 + q] = rsum[q];
  }
  __syncthreads();
  float rscale[4];
  #pragma unroll
  for (int q = 0; q < 4; ++q) {
    const int ri = lg * 4 + q;
    rscale[q] = mrow[q] / fmaxf(redsum[0][wr][ri] + redsum[1][wr][ri], 1e-30f);
  }

  // ---- pass 2: recompute e, scale, column sums ----
  for (int ct = 0; ct < 16; ++ct) {
    const int j0 = cbase + ct * 16;
    const unsigned short* pbt = tbf + (hb + j0 + lr) * DHn + lg * 8;
    bf16x8 tb0 = *(const bf16x8*)pbt;
    bf16x8 tb1 = *(const bf16x8*)(pbt + 32);
    f32x4 tacc = __builtin_amdgcn_mfma_f32_16x16x32_bf16(ta0, tb0, zero4, 0, 0, 0);
    tacc = __builtin_amdgcn_mfma_f32_16x16x32_bf16(ta1, tb1, tacc, 0, 0, 0);
    const float mj = Mcol[j0 + lr];
    float pc = 0.0f;
    #pragma unroll
    for (int q = 0; q < 4; ++q) {
      const float mm = mrow[q] * mj;
      const float st = tacc[q] * 0.125f * mm;
      const float e = __expf(st + (1.0f - mm) * (-10000.0f));
      pc += e * rscale[q];
    }
    pc += __shfl_xor(pc, 16, 64);
    pc += __shfl_xor(pc, 32, 64);
    if (lg == 0) atomicAdd(&gcol[j0 + lr], pc);
  }

  // pair-loss partial
  #pragma unroll
  for (int o = 1; o < 64; o <<= 1) lpair += __shfl_xor(lpair, o, 64);
  if (lane == 0) wred[w] = lpair;
  __syncthreads();

  if (tid == 0) {
    atomicAdd(&acc[0], (double)((wred[0] + wred[1]) + (wred[2] + wred[3])));
  }
  {
    const int j0 = tid, j1 = tid + 256;
    atomicAdd(&g_score[b * Ln + j0], gcol[j0] * Mcol[j0]);
    atomicAdd(&g_score[b * Ln + j1], gcol[j1] * Mcol[j1]);
  }
}

// ---------------------------------------------------------------------------
// Kernel B (+ inline topk_g): one block per (b, h) = 96 blocks. Wave 0
// recomputes the g_score top-k (deterministic, identical across the 12 h
// blocks of a batch); h==0 block also publishes g_top for the triplet kernel.
// Then recompute att rows for those 20 rows, accumulate over h into loc_rows.
// ---------------------------------------------------------------------------
__global__ __launch_bounds__(256, 4) void pairB_kernel(
    const unsigned short* __restrict__ tbf, const float* __restrict__ mask,
    const float* __restrict__ g_score, int* __restrict__ g_top,
    float* __restrict__ loc_rows) {
  const int b = blockIdx.x & 7;
  const int h = blockIdx.x >> 3;
  const int tid = threadIdx.x;
  const int w = tid >> 6, lane = tid & 63;
  const int lr = lane & 15, lg = lane >> 4;
  const int cw = w * 128;

  __shared__ int gidx[32];
  __shared__ float mrow_s[32];
  __shared__ float rscale_s[32];
  __shared__ float redsum[4][32];
  __shared__ float McolB[Ln];
  __shared__ unsigned short es[32][Ln + 8];

  for (int j = tid; j < Ln; j += 256) McolB[j] = mask[b * Ln + j];
  if (w == 1 && lane < 32 - K1n) gidx[K1n + lane] = 0;
  if (w == 0) {
    // single-wave register top-k over g_score[b] (tie -> lowest index)
    float v[8];
    #pragma unroll
    for (int q = 0; q < 8; ++q) v[q] = g_score[b * Ln + q * 64 + lane];
    for (int r = 0; r < K1n; ++r) {
      float bv = v[0]; int bq = 0;
      #pragma unroll
      for (int q = 1; q < 8; ++q) if (v[q] > bv) { bv = v[q]; bq = q; }
      int bj = bq * 64 + lane;
      #pragma unroll
      for (int o = 1; o < 64; o <<= 1) {
        float ov = __shfl_xor(bv, o, 64);
        int oj = __shfl_xor(bj, o, 64);
        if (ov > bv || (ov == bv && oj < bj)) { bv = ov; bj = oj; }
      }
      if (lane == 0) {
        gidx[r] = bj;
        if (h == 0) g_top[b * K1n + r] = bj;
      }
      const int wq = bj >> 6, wl = bj & 63;
      #pragma unroll
      for (int q = 0; q < 8; ++q)
        if (q == wq && lane == wl) v[q] = -3.0e38f;
    }
  }
  __syncthreads();
  if (tid < 32) mrow_s[tid] = (tid < K1n) ? McolB[gidx[tid]] : 0.0f;
  __syncthreads();

  const size_t hb = (size_t)(b * NHn + h) * Ln;
  bf16x8 ta[2][2];
  #pragma unroll
  for (int rt = 0; rt < 2; ++rt) {
    const unsigned short* p = tbf + (hb + gidx[rt * 16 + lr]) * DHn + lg * 8;
    ta[rt][0] = *(const bf16x8*)p;
    ta[rt][1] = *(const bf16x8*)(p + 32);
  }
  const f32x4 zero4 = {0.0f, 0.0f, 0.0f, 0.0f};
  float rsum[2][4] = {{0, 0, 0, 0}, {0, 0, 0, 0}};
  #pragma unroll
  for (int ct = 0; ct < 8; ++ct) {
    const int j0 = cw + ct * 16;
    const unsigned short* pb = tbf + (hb + j0 + lr) * DHn + lg * 8;
    bf16x8 tb0 = *(const bf16x8*)pb;
    bf16x8 tb1 = *(const bf16x8*)(pb + 32);
    const float mj = McolB[j0 + lr];
    #pragma unroll
    for (int rt = 0; rt < 2; ++rt) {
      f32x4 tacc = __builtin_amdgcn_mfma_f32_16x16x32_bf16(ta[rt][0], tb0, zero4, 0, 0, 0);
      tacc = __builtin_amdgcn_mfma_f32_16x16x32_bf16(ta[rt][1], tb1, tacc, 0, 0, 0);
      #pragma unroll
      for (int q = 0; q < 4; ++q) {
        const int ri = rt * 16 + lg * 4 + q;
        const float mm = mrow_s[ri] * mj;
        const float st = tacc[q] * 0.125f * mm;
        const float e = __expf(st + (1.0f - mm) * (-10000.0f));
        rsum[rt][q] += e;
        es[ri][j0 + lr] = f2bf(e);
      }
    }
  }
  #pragma unroll
  for (int o = 1; o < 16; o <<= 1) {
    #pragma unroll
    for (int rt = 0; rt < 2; ++rt)
      #pragma unroll
      for (int q = 0; q < 4; ++q) rsum[rt][q] += __shfl_xor(rsum[rt][q], o, 64);
  }
  if (lr == 0) {
    #pragma unroll
    for (int rt = 0; rt < 2; ++rt)
      #pragma unroll
      for (int q = 0; q < 4; ++q) redsum[w][rt * 16 + lg * 4 + q] = rsum[rt][q];
  }
  __syncthreads();
  if (tid < 32) {
    const float fs = redsum[0][tid] + redsum[1][tid] + redsum[2][tid] + redsum[3][tid];
    rscale_s[tid] = mrow_s[tid] / fmaxf(fs, 1e-30f);
  }
  __syncthreads();
  for (int idx = tid; idx < K1n * Ln; idx += 256) {
    const int ri = idx >> 9, j = idx & (Ln - 1);
    const float e = bf2f(es[ri][j]);
    atomicAdd(&loc_rows[(size_t)(b * K1n + ri) * Ln + j], e * rscale_s[ri] * McolB[j]);
  }
}

// ---------------------------------------------------------------------------
// Triplet (+ inline topk_l, + last-block finalize). One block per (b, i1).
// Wave 0 computes the loc-row top-k; then normalized diffs -> bf16 LDS and
// 20x20 Grams via MFMA. Last-finishing block combines the losses.
// ---------------------------------------------------------------------------
#define TP (Dn + 16)

__global__ __launch_bounds__(256, 1) void triplet_kernel(
    const float* __restrict__ s_rep, const float* __restrict__ t_rep,
    const float* __restrict__ mask, const int* __restrict__ g_top,
    const float* __restrict__ loc_rows, double* __restrict__ acc,
    unsigned int* __restrict__ done_cnt, float* __restrict__ out) {
  const int blk = blockIdx.x, tid = threadIdx.x;
  const int b = blk / K1n, i1 = blk % K1n;
  const int w = tid >> 6, lane = tid & 63;
  const int lr = lane & 15, lg = lane >> 4;

  __shared__ unsigned short NS[32][TP];
  __shared__ unsigned short NT[32][TP];
  __shared__ int lidx[K2n];
  __shared__ float fl2[K2n];
  __shared__ float sred[4], cred[4];
  __shared__ int is_last;
  __shared__ float red[4];

  const int g = g_top[b * K1n + i1];
  if (w == 0) {
    // single-wave top-k of loc_rows[b][i1] with diagonal zeroed
    const float* r0 = loc_rows + (size_t)(b * K1n + i1) * Ln;
    float v[8];
    #pragma unroll
    for (int q = 0; q < 8; ++q) {
      const int j = q * 64 + lane;
      v[q] = (j == g) ? 0.0f : r0[j];
    }
    for (int r = 0; r < K2n; ++r) {
      float bv = v[0]; int bq = 0;
      #pragma unroll
      for (int q = 1; q < 8; ++q) if (v[q] > bv) { bv = v[q]; bq = q; }
      int bj = bq * 64 + lane;
      #pragma unroll
      for (int o = 1; o < 64; o <<= 1) {
        float ov = __shfl_xor(bv, o, 64);
        int oj = __shfl_xor(bj, o, 64);
        if (ov > bv || (ov == bv && oj < bj)) { bv = ov; bj = oj; }
      }
      if (lane == 0) lidx[r] = bj;
      const int wq = bj >> 6, wl = bj & 63;
      #pragma unroll
      for (int q = 0; q < 8; ++q)
        if (q == wq && lane == wl) v[q] = -3.0e38f;
    }
  }
  __syncthreads();
  if (tid < K2n)
    fl2[tid] = (mask[b * Ln + g] + mask[b * Ln + lidx[tid]] == 2.0f) ? 1.0f : 0.0f;
  __syncthreads();

  const float* pgs = s_rep + (size_t)(b * Ln + g) * Dn;
  const float* pgt = t_rep + (size_t)(b * Ln + g) * Dn;
  for (int j = w; j < K2n; j += 4) {
    const float* pls = s_rep + (size_t)(b * Ln + lidx[j]) * Dn;
    const float* plt = t_rep + (size_t)(b * Ln + lidx[j]) * Dn;
    float4 ds[3], dt[3];
    float ssq = 0.0f, tsq = 0.0f;
    #pragma unroll
    for (int q = 0; q < 3; ++q) {
      const int c = lane * 4 + q * 256;
      float4 a = *(const float4*)&pgs[c];
      float4 x = *(const float4*)&pls[c];
      ds[q] = make_float4(a.x - x.x, a.y - x.y, a.z - x.z, a.w - x.w);
      ssq += ds[q].x * ds[q].x + ds[q].y * ds[q].y + ds[q].z * ds[q].z + ds[q].w * ds[q].w;
      float4 c2 = *(const float4*)&pgt[c];
      float4 y = *(const float4*)&plt[c];
      dt[q] = make_float4(c2.x - y.x, c2.y - y.y, c2.z - y.z, c2.w - y.w);
      tsq += dt[q].x * dt[q].x + dt[q].y * dt[q].y + dt[q].z * dt[q].z + dt[q].w * dt[q].w;
    }
    #pragma unroll
    for (int o = 1; o < 64; o <<= 1) {
      ssq += __shfl_xor(ssq, o, 64);
      tsq += __shfl_xor(tsq, o, 64);
    }
    const float sinv = 1.0f / fmaxf(sqrtf(ssq), 1e-12f);
    const float tinv = 1.0f / fmaxf(sqrtf(tsq), 1e-12f);
    #pragma unroll
    for (int q = 0; q < 3; ++q) {
      const int c = lane * 4 + q * 256;
      ushort4 us, ut;
      us.x = f2bf(ds[q].x * sinv); us.y = f2bf(ds[q].y * sinv);
      us.z = f2bf(ds[q].z * sinv); us.w = f2bf(ds[q].w * sinv);
      ut.x = f2bf(dt[q].x * tinv); ut.y = f2bf(dt[q].y * tinv);
      ut.z = f2bf(dt[q].z * tinv); ut.w = f2bf(dt[q].w * tinv);
      *(ushort4*)&NS[j][c] = us;
      *(ushort4*)&NT[j][c] = ut;
    }
  }
  __syncthreads();

  // Gram quadrant per wave: rows qr*16.., cols qc*16..
  const int qr = w >> 1, qc = w & 1;
  f32x4 sacc = {0.0f, 0.0f, 0.0f, 0.0f};
  f32x4 tacc = {0.0f, 0.0f, 0.0f, 0.0f};
  #pragma unroll
  for (int ks = 0; ks < 24; ++ks) {
    const int kk = ks * 32 + lg * 8;
    bf16x8 as = *(const bf16x8*)&NS[qr * 16 + lr][kk];
    bf16x8 bs = *(const bf16x8*)&NS[qc * 16 + lr][kk];
    bf16x8 at = *(const bf16x8*)&NT[qr * 16 + lr][kk];
    bf16x8 bt = *(const bf16x8*)&NT[qc * 16 + lr][kk];
    sacc = __builtin_amdgcn_mfma_f32_16x16x32_bf16(as, bs, sacc, 0, 0, 0);
    tacc = __builtin_amdgcn_mfma_f32_16x16x32_bf16(at, bt, tacc, 0, 0, 0);
  }
  float psum = 0.0f, pcnt = 0.0f;
  #pragma unroll
  for (int q = 0; q < 4; ++q) {
    const int j2 = qr * 16 + lg * 4 + q;    // Gram row
    const int k2 = qc * 16 + lr;            // Gram col
    if (j2 < K2n && k2 < K2n && j2 != k2) {
      const float am = fl2[j2] * fl2[k2];
      const bool smv = (am != 0.0f) && (sacc[q] != 0.0f);
      const bool tmv = (am != 0.0f) && (tacc[q] != 0.0f);
      const float sv = smv ? sacc[q] : 0.0f;
      const float tv = tmv ? tacc[q] : 0.0f;
      const float d = sv - tv;
      const float ad = fabsf(d);
      psum += (ad < 1.0f) ? 0.5f * d * d : (ad - 0.5f);
      pcnt += smv ? 1.0f : 0.0f;
    }
  }
  #pragma unroll
  for (int o = 1; o < 64; o <<= 1) {
    psum += __shfl_xor(psum, o, 64);
    pcnt += __shfl_xor(pcnt, o, 64);
  }
  if (lane == 0) { sred[w] = psum; cred[w] = pcnt; }
  __syncthreads();
  if (tid == 0) {
    atomicAdd(&acc[1], (double)(sred[0] + sred[1] + sred[2] + sred[3]));
    atomicAdd(&acc[2], (double)(cred[0] + cred[1] + cred[2] + cred[3]));
    __threadfence();
    const unsigned int done = atomicAdd(done_cnt, 1u);
    is_last = (done == (unsigned int)(Bn * K1n - 1)) ? 1 : 0;
  }
  __syncthreads();

  // last-finishing block: finalize (all acc atomics from other blocks are
  // visible: each block fenced before its counter increment)
  if (is_last) {
    double sm = 0.0;
    for (int bb = 0; bb < Bn; ++bb) {
      float p = 0.0f;
      for (int i = tid; i < Ln; i += 256) p += mask[bb * Ln + i];
      #pragma unroll
      for (int o = 1; o < 64; o <<= 1) p += __shfl_xor(p, o, 64);
      __syncthreads();
      if ((tid & 63) == 0) red[tid >> 6] = p;
      __syncthreads();
      if (tid == 0) {
        float rs = red[0] + red[1] + red[2] + red[3];
        sm += (double)rs * (double)rs;
      }
    }
    __syncthreads();
    if (tid == 0) {
      const double a0 = atomicAdd(&acc[0], 0.0);   // device-coherent reads
      const double a1 = atomicAdd(&acc[1], 0.0);
      const double a2 = atomicAdd(&acc[2], 0.0);
      const double lp = a0 / ((double)NHn * sm);
      const double lt = a1 / a2;
      out[0] = (float)(lp + lt);
    }
  }
}

// ---------------------------------------------------------------------------
extern "C" void kernel_launch(void* const* d_in, const int* in_sizes, int n_in,
                              void* d_out, int out_size, void* d_ws, size_t ws_size,
                              hipStream_t stream) {
  const float* s_rep = (const float*)d_in[0];
  const float* t_rep = (const float*)d_in[1];
  const float* mask  = (const float*)d_in[2];
  float* out = (float*)d_out;

  char* w = (char*)d_ws;
  double* acc      = (double*)(w + WS_ACC);
  unsigned int* done_cnt = (unsigned int*)(w + WS_ACC + 48);
  float* g_score   = (float*)(w + WS_GSCORE);
  float* loc_rows  = (float*)(w + WS_LOCR);
  int* g_top       = (int*)(w + WS_GTOP);
  unsigned short* sbf = (unsigned short*)(w + WS_SBF);
  unsigned short* tbf = (unsigned short*)(w + WS_TBF);

  hipMemsetAsync(d_ws, 0, WS_ZERO_BYTES, stream);

  prep_bf16_kernel<<<Bn * Ln * Dn / 4 / 256, 256, 0, stream>>>(s_rep, t_rep, sbf, tbf);
  pairA_kernel<<<Bn * NHn * (Ln / 32), 256, 0, stream>>>(sbf, tbf, mask, g_score, acc);
  pairB_kernel<<<Bn * NHn, 256, 0, stream>>>(tbf, mask, g_score, g_top, loc_rows);
  triplet_kernel<<<Bn * K1n, 256, 0, stream>>>(s_rep, t_rep, mask, g_top, loc_rows,
                                               acc, done_cnt, out);
}

// Round 9
// 147.670 us; speedup vs baseline: 1.1722x; 1.1722x over previous
//
#include <hip/hip_runtime.h>
#include <hip/hip_bf16.h>
#include <math.h>

#define Bn 8
#define Ln 512
#define Dn 768
#define NHn 12
#define DHn 64
#define K1n 20
#define K2n 20

// workspace layout (bytes)
#define WS_ACC    0          // double acc[8]: [0]=pair_num [1]=trip_num [2]=trip_cnt; bytes 48..51 = done-counter
#define WS_GSCORE 64         // float g_score[8*512]
#define WS_LOCR   16448      // float loc_rows[8*20*512] (320 KB)
#define WS_GTOP   344128     // int g_top[8*20]
#define WS_SBF    357568     // ushort sbf[8*12*512*64] bf16 head-major
#define WS_TBF    6649024    // ushort tbf[...] (ends 12940480)
#define WS_ZERO_BYTES 344128 // acc + counter + g_score + loc_rows

typedef __attribute__((ext_vector_type(8))) short bf16x8;
typedef __attribute__((ext_vector_type(4))) float f32x4;

__device__ inline unsigned short f2bf(float x) {
  __hip_bfloat16 h = __float2bfloat16(x);
  return *reinterpret_cast<unsigned short*>(&h);
}
__device__ inline float bf2f(unsigned short u) {
  return __uint_as_float(((unsigned int)u) << 16);
}

// ---------------------------------------------------------------------------
// Prep: fp32 [b][row][h*64+k] -> bf16 head-major [b][h][row][k]
// ---------------------------------------------------------------------------
__global__ __launch_bounds__(256) void prep_bf16_kernel(
    const float* __restrict__ s, const float* __restrict__ t,
    unsigned short* __restrict__ sbf, unsigned short* __restrict__ tbf) {
  int gid = blockIdx.x * 256 + threadIdx.x;
  int f = gid * 4;
  int col = f % Dn;
  int rb = f / Dn;
  int row = rb & (Ln - 1);
  int b = rb >> 9;
  int h = col >> 6;
  int k = col & 63;
  size_t dst = (((size_t)(b * NHn + h) * Ln + row) * DHn + k);
  float4 vs = *(const float4*)(s + f);
  float4 vt = *(const float4*)(t + f);
  ushort4 us, ut;
  us.x = f2bf(vs.x); us.y = f2bf(vs.y); us.z = f2bf(vs.z); us.w = f2bf(vs.w);
  ut.x = f2bf(vt.x); ut.y = f2bf(vt.y); ut.z = f2bf(vt.z); ut.w = f2bf(vt.w);
  *(ushort4*)(sbf + dst) = us;
  *(ushort4*)(tbf + dst) = ut;
}

// ---------------------------------------------------------------------------
// Kernel A (two-pass recompute, column-split): one block per (b, h, 32-row
// tile). Wave (wr,wc) owns 16 rows x 256 cols -> grid 1536 = 6 blocks/CU.
// NOTE: the ct loops MUST stay rolled (#pragma unroll 1). Round 8 let the
// compiler fully unroll the 16-iteration loops -> 212 VGPRs -> 11% occupancy
// -> 1.5x slower. Rolled: ~50 VGPRs, ~75% occupancy.
// ---------------------------------------------------------------------------
__global__ __launch_bounds__(256) void pairA_kernel(
    const unsigned short* __restrict__ sbf, const unsigned short* __restrict__ tbf,
    const float* __restrict__ mask, float* __restrict__ g_score,
    double* __restrict__ acc) {
  const int b = blockIdx.x & 7;
  const int r = blockIdx.x >> 3;          // 0..191
  const int it = r / NHn;                 // 0..15
  const int h = r - it * NHn;             // 0..11
  const int tid = threadIdx.x;
  const int w = tid >> 6;
  const int wr = w >> 1;                  // row strip 0/1
  const int wc = w & 1;                   // col half 0/1
  const int lane = tid & 63;
  const int lr = lane & 15, lg = lane >> 4;

  __shared__ float Mcol[Ln];
  __shared__ float gcol[Ln];
  __shared__ float redsum[2][2][16];      // [wc][wr][row]
  __shared__ float wred[4];

  for (int j = tid; j < Ln; j += 256) {
    Mcol[j] = mask[b * Ln + j];
    gcol[j] = 0.0f;
  }
  __syncthreads();

  const size_t hb = (size_t)(b * NHn + h) * Ln;
  const int rw = it * 32 + wr * 16;
  const unsigned short* pas = sbf + (hb + rw + lr) * DHn + lg * 8;
  const unsigned short* pat = tbf + (hb + rw + lr) * DHn + lg * 8;
  bf16x8 sa0 = *(const bf16x8*)pas;
  bf16x8 sa1 = *(const bf16x8*)(pas + 32);
  bf16x8 ta0 = *(const bf16x8*)pat;
  bf16x8 ta1 = *(const bf16x8*)(pat + 32);
  float mrow[4];
  #pragma unroll
  for (int q = 0; q < 4; ++q) mrow[q] = Mcol[rw + lg * 4 + q];

  const f32x4 zero4 = {0.0f, 0.0f, 0.0f, 0.0f};
  const int cbase = wc * 256;
  float lpair = 0.0f;
  float rsum[4] = {0.0f, 0.0f, 0.0f, 0.0f};

  // ---- pass 1: diff^2 + unnormalized row sums over this wave's 256 cols ----
  #pragma unroll 1
  for (int ct = 0; ct < 16; ++ct) {
    const int j0 = cbase + ct * 16;
    const unsigned short* pbs = sbf + (hb + j0 + lr) * DHn + lg * 8;
    const unsigned short* pbt = tbf + (hb + j0 + lr) * DHn + lg * 8;
    bf16x8 sb0 = *(const bf16x8*)pbs;
    bf16x8 sb1 = *(const bf16x8*)(pbs + 32);
    bf16x8 tb0 = *(const bf16x8*)pbt;
    bf16x8 tb1 = *(const bf16x8*)(pbt + 32);
    f32x4 sacc = __builtin_amdgcn_mfma_f32_16x16x32_bf16(sa0, sb0, zero4, 0, 0, 0);
    sacc = __builtin_amdgcn_mfma_f32_16x16x32_bf16(sa1, sb1, sacc, 0, 0, 0);
    f32x4 tacc = __builtin_amdgcn_mfma_f32_16x16x32_bf16(ta0, tb0, zero4, 0, 0, 0);
    tacc = __builtin_amdgcn_mfma_f32_16x16x32_bf16(ta1, tb1, tacc, 0, 0, 0);
    const float mj = Mcol[j0 + lr];
    #pragma unroll
    for (int q = 0; q < 4; ++q) {
      const float mm = mrow[q] * mj;
      const float ss = sacc[q] * 0.125f * mm;
      const float st = tacc[q] * 0.125f * mm;
      const float d = ss - st;
      lpair += d * d;
      rsum[q] += __expf(st + (1.0f - mm) * (-10000.0f));
    }
  }

  // wave-local partial row sums -> LDS exchange across col halves
  #pragma unroll
  for (int o = 1; o < 16; o <<= 1) {
    #pragma unroll
    for (int q = 0; q < 4; ++q) rsum[q] += __shfl_xor(rsum[q], o, 64);
  }
  if (lr == 0) {
    #pragma unroll
    for (int q = 0; q < 4; ++q) redsum[wc][wr][lg * 4 + q] = rsum[q];
  }
  __syncthreads();
  float rscale[4];
  #pragma unroll
  for (int q = 0; q < 4; ++q) {
    const int ri = lg * 4 + q;
    rscale[q] = mrow[q] / fmaxf(redsum[0][wr][ri] + redsum[1][wr][ri], 1e-30f);
  }

  // ---- pass 2: recompute e, scale, column sums ----
  #pragma unroll 1
  for (int ct = 0; ct < 16; ++ct) {
    const int j0 = cbase + ct * 16;
    const unsigned short* pbt = tbf + (hb + j0 + lr) * DHn + lg * 8;
    bf16x8 tb0 = *(const bf16x8*)pbt;
    bf16x8 tb1 = *(const bf16x8*)(pbt + 32);
    f32x4 tacc = __builtin_amdgcn_mfma_f32_16x16x32_bf16(ta0, tb0, zero4, 0, 0, 0);
    tacc = __builtin_amdgcn_mfma_f32_16x16x32_bf16(ta1, tb1, tacc, 0, 0, 0);
    const float mj = Mcol[j0 + lr];
    float pc = 0.0f;
    #pragma unroll
    for (int q = 0; q < 4; ++q) {
      const float mm = mrow[q] * mj;
      const float st = tacc[q] * 0.125f * mm;
      const float e = __expf(st + (1.0f - mm) * (-10000.0f));
      pc += e * rscale[q];
    }
    pc += __shfl_xor(pc, 16, 64);
    pc += __shfl_xor(pc, 32, 64);
    if (lg == 0) atomicAdd(&gcol[j0 + lr], pc);
  }

  // pair-loss partial
  #pragma unroll
  for (int o = 1; o < 64; o <<= 1) lpair += __shfl_xor(lpair, o, 64);
  if (lane == 0) wred[w] = lpair;
  __syncthreads();

  if (tid == 0) {
    atomicAdd(&acc[0], (double)((wred[0] + wred[1]) + (wred[2] + wred[3])));
  }
  {
    const int j0 = tid, j1 = tid + 256;
    atomicAdd(&g_score[b * Ln + j0], gcol[j0] * Mcol[j0]);
    atomicAdd(&g_score[b * Ln + j1], gcol[j1] * Mcol[j1]);
  }
}

// ---------------------------------------------------------------------------
// Kernel B (+ inline topk_g): one block per (b, h) = 96 blocks. Wave 0
// recomputes the g_score top-k (deterministic, identical across the 12 h
// blocks of a batch); h==0 block also publishes g_top for the triplet kernel.
// Then recompute att rows for those 20 rows, accumulate over h into loc_rows.
// ---------------------------------------------------------------------------
__global__ __launch_bounds__(256, 4) void pairB_kernel(
    const unsigned short* __restrict__ tbf, const float* __restrict__ mask,
    const float* __restrict__ g_score, int* __restrict__ g_top,
    float* __restrict__ loc_rows) {
  const int b = blockIdx.x & 7;
  const int h = blockIdx.x >> 3;
  const int tid = threadIdx.x;
  const int w = tid >> 6, lane = tid & 63;
  const int lr = lane & 15, lg = lane >> 4;
  const int cw = w * 128;

  __shared__ int gidx[32];
  __shared__ float mrow_s[32];
  __shared__ float rscale_s[32];
  __shared__ float redsum[4][32];
  __shared__ float McolB[Ln];
  __shared__ unsigned short es[32][Ln + 8];

  for (int j = tid; j < Ln; j += 256) McolB[j] = mask[b * Ln + j];
  if (w == 1 && lane < 32 - K1n) gidx[K1n + lane] = 0;
  if (w == 0) {
    // single-wave register top-k over g_score[b] (tie -> lowest index)
    float v[8];
    #pragma unroll
    for (int q = 0; q < 8; ++q) v[q] = g_score[b * Ln + q * 64 + lane];
    for (int r = 0; r < K1n; ++r) {
      float bv = v[0]; int bq = 0;
      #pragma unroll
      for (int q = 1; q < 8; ++q) if (v[q] > bv) { bv = v[q]; bq = q; }
      int bj = bq * 64 + lane;
      #pragma unroll
      for (int o = 1; o < 64; o <<= 1) {
        float ov = __shfl_xor(bv, o, 64);
        int oj = __shfl_xor(bj, o, 64);
        if (ov > bv || (ov == bv && oj < bj)) { bv = ov; bj = oj; }
      }
      if (lane == 0) {
        gidx[r] = bj;
        if (h == 0) g_top[b * K1n + r] = bj;
      }
      const int wq = bj >> 6, wl = bj & 63;
      #pragma unroll
      for (int q = 0; q < 8; ++q)
        if (q == wq && lane == wl) v[q] = -3.0e38f;
    }
  }
  __syncthreads();
  if (tid < 32) mrow_s[tid] = (tid < K1n) ? McolB[gidx[tid]] : 0.0f;
  __syncthreads();

  const size_t hb = (size_t)(b * NHn + h) * Ln;
  bf16x8 ta[2][2];
  #pragma unroll
  for (int rt = 0; rt < 2; ++rt) {
    const unsigned short* p = tbf + (hb + gidx[rt * 16 + lr]) * DHn + lg * 8;
    ta[rt][0] = *(const bf16x8*)p;
    ta[rt][1] = *(const bf16x8*)(p + 32);
  }
  const f32x4 zero4 = {0.0f, 0.0f, 0.0f, 0.0f};
  float rsum[2][4] = {{0, 0, 0, 0}, {0, 0, 0, 0}};
  #pragma unroll 1
  for (int ct = 0; ct < 8; ++ct) {
    const int j0 = cw + ct * 16;
    const unsigned short* pb = tbf + (hb + j0 + lr) * DHn + lg * 8;
    bf16x8 tb0 = *(const bf16x8*)pb;
    bf16x8 tb1 = *(const bf16x8*)(pb + 32);
    const float mj = McolB[j0 + lr];
    #pragma unroll
    for (int rt = 0; rt < 2; ++rt) {
      f32x4 tacc = __builtin_amdgcn_mfma_f32_16x16x32_bf16(ta[rt][0], tb0, zero4, 0, 0, 0);
      tacc = __builtin_amdgcn_mfma_f32_16x16x32_bf16(ta[rt][1], tb1, tacc, 0, 0, 0);
      #pragma unroll
      for (int q = 0; q < 4; ++q) {
        const int ri = rt * 16 + lg * 4 + q;
        const float mm = mrow_s[ri] * mj;
        const float st = tacc[q] * 0.125f * mm;
        const float e = __expf(st + (1.0f - mm) * (-10000.0f));
        rsum[rt][q] += e;
        es[ri][j0 + lr] = f2bf(e);
      }
    }
  }
  #pragma unroll
  for (int o = 1; o < 16; o <<= 1) {
    #pragma unroll
    for (int rt = 0; rt < 2; ++rt)
      #pragma unroll
      for (int q = 0; q < 4; ++q) rsum[rt][q] += __shfl_xor(rsum[rt][q], o, 64);
  }
  if (lr == 0) {
    #pragma unroll
    for (int rt = 0; rt < 2; ++rt)
      #pragma unroll
      for (int q = 0; q < 4; ++q) redsum[w][rt * 16 + lg * 4 + q] = rsum[rt][q];
  }
  __syncthreads();
  if (tid < 32) {
    const float fs = redsum[0][tid] + redsum[1][tid] + redsum[2][tid] + redsum[3][tid];
    rscale_s[tid] = mrow_s[tid] / fmaxf(fs, 1e-30f);
  }
  __syncthreads();
  for (int idx = tid; idx < K1n * Ln; idx += 256) {
    const int ri = idx >> 9, j = idx & (Ln - 1);
    const float e = bf2f(es[ri][j]);
    atomicAdd(&loc_rows[(size_t)(b * K1n + ri) * Ln + j], e * rscale_s[ri] * McolB[j]);
  }
}

// ---------------------------------------------------------------------------
// Triplet (+ inline topk_l, + last-block finalize). One block per (b, i1).
// Wave 0 computes the loc-row top-k; then normalized diffs -> bf16 LDS and
// 20x20 Grams via MFMA. Last-finishing block combines the losses.
// ---------------------------------------------------------------------------
#define TP (Dn + 16)

__global__ __launch_bounds__(256, 1) void triplet_kernel(
    const float* __restrict__ s_rep, const float* __restrict__ t_rep,
    const float* __restrict__ mask, const int* __restrict__ g_top,
    const float* __restrict__ loc_rows, double* __restrict__ acc,
    unsigned int* __restrict__ done_cnt, float* __restrict__ out) {
  const int blk = blockIdx.x, tid = threadIdx.x;
  const int b = blk / K1n, i1 = blk % K1n;
  const int w = tid >> 6, lane = tid & 63;
  const int lr = lane & 15, lg = lane >> 4;

  __shared__ unsigned short NS[32][TP];
  __shared__ unsigned short NT[32][TP];
  __shared__ int lidx[K2n];
  __shared__ float fl2[K2n];
  __shared__ float sred[4], cred[4];
  __shared__ int is_last;
  __shared__ float red[4];

  const int g = g_top[b * K1n + i1];
  if (w == 0) {
    // single-wave top-k of loc_rows[b][i1] with diagonal zeroed
    const float* r0 = loc_rows + (size_t)(b * K1n + i1) * Ln;
    float v[8];
    #pragma unroll
    for (int q = 0; q < 8; ++q) {
      const int j = q * 64 + lane;
      v[q] = (j == g) ? 0.0f : r0[j];
    }
    for (int r = 0; r < K2n; ++r) {
      float bv = v[0]; int bq = 0;
      #pragma unroll
      for (int q = 1; q < 8; ++q) if (v[q] > bv) { bv = v[q]; bq = q; }
      int bj = bq * 64 + lane;
      #pragma unroll
      for (int o = 1; o < 64; o <<= 1) {
        float ov = __shfl_xor(bv, o, 64);
        int oj = __shfl_xor(bj, o, 64);
        if (ov > bv || (ov == bv && oj < bj)) { bv = ov; bj = oj; }
      }
      if (lane == 0) lidx[r] = bj;
      const int wq = bj >> 6, wl = bj & 63;
      #pragma unroll
      for (int q = 0; q < 8; ++q)
        if (q == wq && lane == wl) v[q] = -3.0e38f;
    }
  }
  __syncthreads();
  if (tid < K2n)
    fl2[tid] = (mask[b * Ln + g] + mask[b * Ln + lidx[tid]] == 2.0f) ? 1.0f : 0.0f;
  __syncthreads();

  const float* pgs = s_rep + (size_t)(b * Ln + g) * Dn;
  const float* pgt = t_rep + (size_t)(b * Ln + g) * Dn;
  for (int j = w; j < K2n; j += 4) {
    const float* pls = s_rep + (size_t)(b * Ln + lidx[j]) * Dn;
    const float* plt = t_rep + (size_t)(b * Ln + lidx[j]) * Dn;
    float4 ds[3], dt[3];
    float ssq = 0.0f, tsq = 0.0f;
    #pragma unroll
    for (int q = 0; q < 3; ++q) {
      const int c = lane * 4 + q * 256;
      float4 a = *(const float4*)&pgs[c];
      float4 x = *(const float4*)&pls[c];
      ds[q] = make_float4(a.x - x.x, a.y - x.y, a.z - x.z, a.w - x.w);
      ssq += ds[q].x * ds[q].x + ds[q].y * ds[q].y + ds[q].z * ds[q].z + ds[q].w * ds[q].w;
      float4 c2 = *(const float4*)&pgt[c];
      float4 y = *(const float4*)&plt[c];
      dt[q] = make_float4(c2.x - y.x, c2.y - y.y, c2.z - y.z, c2.w - y.w);
      tsq += dt[q].x * dt[q].x + dt[q].y * dt[q].y + dt[q].z * dt[q].z + dt[q].w * dt[q].w;
    }
    #pragma unroll
    for (int o = 1; o < 64; o <<= 1) {
      ssq += __shfl_xor(ssq, o, 64);
      tsq += __shfl_xor(tsq, o, 64);
    }
    const float sinv = 1.0f / fmaxf(sqrtf(ssq), 1e-12f);
    const float tinv = 1.0f / fmaxf(sqrtf(tsq), 1e-12f);
    #pragma unroll
    for (int q = 0; q < 3; ++q) {
      const int c = lane * 4 + q * 256;
      ushort4 us, ut;
      us.x = f2bf(ds[q].x * sinv); us.y = f2bf(ds[q].y * sinv);
      us.z = f2bf(ds[q].z * sinv); us.w = f2bf(ds[q].w * sinv);
      ut.x = f2bf(dt[q].x * tinv); ut.y = f2bf(dt[q].y * tinv);
      ut.z = f2bf(dt[q].z * tinv); ut.w = f2bf(dt[q].w * tinv);
      *(ushort4*)&NS[j][c] = us;
      *(ushort4*)&NT[j][c] = ut;
    }
  }
  __syncthreads();

  // Gram quadrant per wave: rows qr*16.., cols qc*16..
  const int qr = w >> 1, qc = w & 1;
  f32x4 sacc = {0.0f, 0.0f, 0.0f, 0.0f};
  f32x4 tacc = {0.0f, 0.0f, 0.0f, 0.0f};
  #pragma unroll
  for (int ks = 0; ks < 24; ++ks) {
    const int kk = ks * 32 + lg * 8;
    bf16x8 as = *(const bf16x8*)&NS[qr * 16 + lr][kk];
    bf16x8 bs = *(const bf16x8*)&NS[qc * 16 + lr][kk];
    bf16x8 at = *(const bf16x8*)&NT[qr * 16 + lr][kk];
    bf16x8 bt = *(const bf16x8*)&NT[qc * 16 + lr][kk];
    sacc = __builtin_amdgcn_mfma_f32_16x16x32_bf16(as, bs, sacc, 0, 0, 0);
    tacc = __builtin_amdgcn_mfma_f32_16x16x32_bf16(at, bt, tacc, 0, 0, 0);
  }
  float psum = 0.0f, pcnt = 0.0f;
  #pragma unroll
  for (int q = 0; q < 4; ++q) {
    const int j2 = qr * 16 + lg * 4 + q;    // Gram row
    const int k2 = qc * 16 + lr;            // Gram col
    if (j2 < K2n && k2 < K2n && j2 != k2) {
      const float am = fl2[j2] * fl2[k2];
      const bool smv = (am != 0.0f) && (sacc[q] != 0.0f);
      const bool tmv = (am != 0.0f) && (tacc[q] != 0.0f);
      const float sv = smv ? sacc[q] : 0.0f;
      const float tv = tmv ? tacc[q] : 0.0f;
      const float d = sv - tv;
      const float ad = fabsf(d);
      psum += (ad < 1.0f) ? 0.5f * d * d : (ad - 0.5f);
      pcnt += smv ? 1.0f : 0.0f;
    }
  }
  #pragma unroll
  for (int o = 1; o < 64; o <<= 1) {
    psum += __shfl_xor(psum, o, 64);
    pcnt += __shfl_xor(pcnt, o, 64);
  }
  if (lane == 0) { sred[w] = psum; cred[w] = pcnt; }
  __syncthreads();
  if (tid == 0) {
    atomicAdd(&acc[1], (double)(sred[0] + sred[1] + sred[2] + sred[3]));
    atomicAdd(&acc[2], (double)(cred[0] + cred[1] + cred[2] + cred[3]));
    __threadfence();
    const unsigned int done = atomicAdd(done_cnt, 1u);
    is_last = (done == (unsigned int)(Bn * K1n - 1)) ? 1 : 0;
  }
  __syncthreads();

  // last-finishing block: finalize (all acc atomics from other blocks are
  // visible: each block fenced before its counter increment)
  if (is_last) {
    double sm = 0.0;
    for (int bb = 0; bb < Bn; ++bb) {
      float p = 0.0f;
      for (int i = tid; i < Ln; i += 256) p += mask[bb * Ln + i];
      #pragma unroll
      for (int o = 1; o < 64; o <<= 1) p += __shfl_xor(p, o, 64);
      __syncthreads();
      if ((tid & 63) == 0) red[tid >> 6] = p;
      __syncthreads();
      if (tid == 0) {
        float rs = red[0] + red[1] + red[2] + red[3];
        sm += (double)rs * (double)rs;
      }
    }
    __syncthreads();
    if (tid == 0) {
      const double a0 = atomicAdd(&acc[0], 0.0);   // device-coherent reads
      const double a1 = atomicAdd(&acc[1], 0.0);
      const double a2 = atomicAdd(&acc[2], 0.0);
      const double lp = a0 / ((double)NHn * sm);
      const double lt = a1 / a2;
      out[0] = (float)(lp + lt);
    }
  }
}

// ---------------------------------------------------------------------------
extern "C" void kernel_launch(void* const* d_in, const int* in_sizes, int n_in,
                              void* d_out, int out_size, void* d_ws, size_t ws_size,
                              hipStream_t stream) {
  const float* s_rep = (const float*)d_in[0];
  const float* t_rep = (const float*)d_in[1];
  const float* mask  = (const float*)d_in[2];
  float* out = (float*)d_out;

  char* w = (char*)d_ws;
  double* acc      = (double*)(w + WS_ACC);
  unsigned int* done_cnt = (unsigned int*)(w + WS_ACC + 48);
  float* g_score   = (float*)(w + WS_GSCORE);
  float* loc_rows  = (float*)(w + WS_LOCR);
  int* g_top       = (int*)(w + WS_GTOP);
  unsigned short* sbf = (unsigned short*)(w + WS_SBF);
  unsigned short* tbf = (unsigned short*)(w + WS_TBF);

  hipMemsetAsync(d_ws, 0, WS_ZERO_BYTES, stream);

  prep_bf16_kernel<<<Bn * Ln * Dn / 4 / 256, 256, 0, stream>>>(s_rep, t_rep, sbf, tbf);
  pairA_kernel<<<Bn * NHn * (Ln / 32), 256, 0, stream>>>(sbf, tbf, mask, g_score, acc);
  pairB_kernel<<<Bn * NHn, 256, 0, stream>>>(tbf, mask, g_score, g_top, loc_rows);
  triplet_kernel<<<Bn * K1n, 256, 0, stream>>>(s_rep, t_rep, mask, g_top, loc_rows,
                                               acc, done_cnt, out);
}

// Round 10
// 126.534 us; speedup vs baseline: 1.3680x; 1.1670x over previous
//
#include <hip/hip_runtime.h>
#include <hip/hip_bf16.h>
#include <math.h>

#define Bn 8
#define Ln 512
#define Dn 768
#define NHn 12
#define DHn 64
#define K1n 20
#define K2n 20
#define BST 72   // LDS B-tile row stride in shorts (64 + 8 pad = 144B rows)

// workspace layout (bytes)
#define WS_ACC    0          // double acc[8]; bytes 48..51 = done-counter
#define WS_GSCORE 64         // float g_score[8*512]
#define WS_LOCR   16448      // float loc_rows[8*20*512] (320 KB)
#define WS_GTOP   344128     // int g_top[8*20]
#define WS_SBF    357568     // ushort sbf[8*12*512*64] bf16 head-major
#define WS_TBF    6649024    // ushort tbf[...] (ends 12940480)
#define WS_ZERO_BYTES 344128 // acc + counter + g_score + loc_rows

typedef __attribute__((ext_vector_type(8))) short bf16x8;
typedef __attribute__((ext_vector_type(4))) float f32x4;

__device__ inline unsigned short f2bf(float x) {
  __hip_bfloat16 h = __float2bfloat16(x);
  return *reinterpret_cast<unsigned short*>(&h);
}
__device__ inline float bf2f(unsigned short u) {
  return __uint_as_float(((unsigned int)u) << 16);
}

// ---------------------------------------------------------------------------
// Prep: fp32 [b][row][h*64+k] -> bf16 head-major [b][h][row][k]
// ---------------------------------------------------------------------------
__global__ __launch_bounds__(256) void prep_bf16_kernel(
    const float* __restrict__ s, const float* __restrict__ t,
    unsigned short* __restrict__ sbf, unsigned short* __restrict__ tbf) {
  int gid = blockIdx.x * 256 + threadIdx.x;
  int f = gid * 4;
  int col = f % Dn;
  int rb = f / Dn;
  int row = rb & (Ln - 1);
  int b = rb >> 9;
  int h = col >> 6;
  int k = col & 63;
  size_t dst = (((size_t)(b * NHn + h) * Ln + row) * DHn + k);
  float4 vs = *(const float4*)(s + f);
  float4 vt = *(const float4*)(t + f);
  ushort4 us, ut;
  us.x = f2bf(vs.x); us.y = f2bf(vs.y); us.z = f2bf(vs.z); us.w = f2bf(vs.w);
  ut.x = f2bf(vt.x); ut.y = f2bf(vt.y); ut.z = f2bf(vt.z); ut.w = f2bf(vt.w);
  *(ushort4*)(sbf + dst) = us;
  *(ushort4*)(tbf + dst) = ut;
}

// ---------------------------------------------------------------------------
// Kernel A v3: LDS-staged B-tiles. One block per (b, h, 32-row tile), 4 waves
// (wr = 16-row strip, wc = 64-col half of the 128-col tile). Round 9 read
// MFMA fragments directly from global: stride-128B gathers -> 16 L2
// transactions per load + no prefetch distance -> latency-bound at ~80us
// regardless of occupancy. Staging: coalesced 1KB/wave burst loads into
// [128][72]-short LDS (row pad kills the 16-way bank conflict), fragments
// read from LDS. Two-pass recompute (pass 2 re-stages t only).
// ct loops stay bounded-unrolled (4 iters); tile loops rolled (#pragma
// unroll 1) to keep VGPR ~80 (round 8 lesson: 212 VGPR = 11% occupancy).
// ---------------------------------------------------------------------------
__global__ __launch_bounds__(256) void pairA_kernel(
    const unsigned short* __restrict__ sbf, const unsigned short* __restrict__ tbf,
    const float* __restrict__ mask, float* __restrict__ g_score,
    double* __restrict__ acc) {
  const int b = blockIdx.x & 7;
  const int r = blockIdx.x >> 3;          // 0..191
  const int it = r / NHn;                 // 0..15
  const int h = r - it * NHn;             // 0..11
  const int tid = threadIdx.x;
  const int w = tid >> 6;
  const int wr = w >> 1;                  // row strip 0/1
  const int wc = w & 1;                   // col half of tile 0/1
  const int lane = tid & 63;
  const int lr = lane & 15, lg = lane >> 4;

  __shared__ unsigned short Bs[128 * BST];
  __shared__ unsigned short Bt[128 * BST];
  __shared__ float Mcol[Ln];
  __shared__ float gcol[Ln];
  __shared__ float redsum[2][2][16];      // [wc][wr][row]
  __shared__ float wred[4];

  for (int j = tid; j < Ln; j += 256) {
    Mcol[j] = mask[b * Ln + j];
    gcol[j] = 0.0f;
  }

  const size_t hb = (size_t)(b * NHn + h) * Ln;
  const int rw = it * 32 + wr * 16;
  // A fragments (one-time gather; rows rw+lr, k = lg*8 / +32)
  const unsigned short* pas = sbf + (hb + rw + lr) * DHn + lg * 8;
  const unsigned short* pat = tbf + (hb + rw + lr) * DHn + lg * 8;
  bf16x8 sa0 = *(const bf16x8*)pas;
  bf16x8 sa1 = *(const bf16x8*)(pas + 32);
  bf16x8 ta0 = *(const bf16x8*)pat;
  bf16x8 ta1 = *(const bf16x8*)(pat + 32);
  __syncthreads();
  float mrow[4];
  #pragma unroll
  for (int q = 0; q < 4; ++q) mrow[q] = Mcol[rw + lg * 4 + q];

  const f32x4 zero4 = {0.0f, 0.0f, 0.0f, 0.0f};
  float lpair = 0.0f;
  float rsum[4] = {0.0f, 0.0f, 0.0f, 0.0f};

  // ---- pass 1: diff^2 + unnormalized row sums ----
  #pragma unroll 1
  for (int t = 0; t < 4; ++t) {
    const int jt = t * 128;
    // stage s tile (coalesced: 64-lane wave reads 8 contiguous 128B rows)
    #pragma unroll
    for (int idx = tid; idx < 1024; idx += 256) {
      const int rr = idx >> 3, cc = idx & 7;
      *(bf16x8*)&Bs[rr * BST + cc * 8] =
          *(const bf16x8*)(sbf + (hb + jt + rr) * DHn + cc * 8);
    }
    #pragma unroll
    for (int idx = tid; idx < 1024; idx += 256) {
      const int rr = idx >> 3, cc = idx & 7;
      *(bf16x8*)&Bt[rr * BST + cc * 8] =
          *(const bf16x8*)(tbf + (hb + jt + rr) * DHn + cc * 8);
    }
    __syncthreads();
    #pragma unroll
    for (int c = 0; c < 4; ++c) {
      const int jl = wc * 64 + c * 16;    // tile-local col base
      const int j0 = jt + jl;             // global col base
      const unsigned short* pbs = &Bs[(jl + lr) * BST + lg * 8];
      const unsigned short* pbt = &Bt[(jl + lr) * BST + lg * 8];
      bf16x8 sb0 = *(const bf16x8*)pbs;
      bf16x8 sb1 = *(const bf16x8*)(pbs + 32);
      bf16x8 tb0 = *(const bf16x8*)pbt;
      bf16x8 tb1 = *(const bf16x8*)(pbt + 32);
      f32x4 sacc = __builtin_amdgcn_mfma_f32_16x16x32_bf16(sa0, sb0, zero4, 0, 0, 0);
      sacc = __builtin_amdgcn_mfma_f32_16x16x32_bf16(sa1, sb1, sacc, 0, 0, 0);
      f32x4 tacc = __builtin_amdgcn_mfma_f32_16x16x32_bf16(ta0, tb0, zero4, 0, 0, 0);
      tacc = __builtin_amdgcn_mfma_f32_16x16x32_bf16(ta1, tb1, tacc, 0, 0, 0);
      const float mj = Mcol[j0 + lr];
      #pragma unroll
      for (int q = 0; q < 4; ++q) {
        const float mm = mrow[q] * mj;
        const float ss = sacc[q] * 0.125f * mm;
        const float st = tacc[q] * 0.125f * mm;
        const float d = ss - st;
        lpair += d * d;
        rsum[q] += __expf(st + (1.0f - mm) * (-10000.0f));
      }
    }
    __syncthreads();
  }

  // wave-local partial row sums -> LDS exchange across col halves
  #pragma unroll
  for (int o = 1; o < 16; o <<= 1) {
    #pragma unroll
    for (int q = 0; q < 4; ++q) rsum[q] += __shfl_xor(rsum[q], o, 64);
  }
  if (lr == 0) {
    #pragma unroll
    for (int q = 0; q < 4; ++q) redsum[wc][wr][lg * 4 + q] = rsum[q];
  }
  __syncthreads();
  float rscale[4];
  #pragma unroll
  for (int q = 0; q < 4; ++q) {
    const int ri = lg * 4 + q;
    rscale[q] = mrow[q] / fmaxf(redsum[0][wr][ri] + redsum[1][wr][ri], 1e-30f);
  }

  // ---- pass 2: re-stage t, recompute e, scale, column sums ----
  #pragma unroll 1
  for (int t = 0; t < 4; ++t) {
    const int jt = t * 128;
    #pragma unroll
    for (int idx = tid; idx < 1024; idx += 256) {
      const int rr = idx >> 3, cc = idx & 7;
      *(bf16x8*)&Bt[rr * BST + cc * 8] =
          *(const bf16x8*)(tbf + (hb + jt + rr) * DHn + cc * 8);
    }
    __syncthreads();
    #pragma unroll
    for (int c = 0; c < 4; ++c) {
      const int jl = wc * 64 + c * 16;
      const int j0 = jt + jl;
      const unsigned short* pbt = &Bt[(jl + lr) * BST + lg * 8];
      bf16x8 tb0 = *(const bf16x8*)pbt;
      bf16x8 tb1 = *(const bf16x8*)(pbt + 32);
      f32x4 tacc = __builtin_amdgcn_mfma_f32_16x16x32_bf16(ta0, tb0, zero4, 0, 0, 0);
      tacc = __builtin_amdgcn_mfma_f32_16x16x32_bf16(ta1, tb1, tacc, 0, 0, 0);
      const float mj = Mcol[j0 + lr];
      float pc = 0.0f;
      #pragma unroll
      for (int q = 0; q < 4; ++q) {
        const float mm = mrow[q] * mj;
        const float st = tacc[q] * 0.125f * mm;
        const float e = __expf(st + (1.0f - mm) * (-10000.0f));
        pc += e * rscale[q];
      }
      pc += __shfl_xor(pc, 16, 64);
      pc += __shfl_xor(pc, 32, 64);
      if (lg == 0) atomicAdd(&gcol[j0 + lr], pc);
    }
    __syncthreads();
  }

  // pair-loss partial
  #pragma unroll
  for (int o = 1; o < 64; o <<= 1) lpair += __shfl_xor(lpair, o, 64);
  if (lane == 0) wred[w] = lpair;
  __syncthreads();

  if (tid == 0) {
    atomicAdd(&acc[0], (double)((wred[0] + wred[1]) + (wred[2] + wred[3])));
  }
  {
    const int j0 = tid, j1 = tid + 256;
    atomicAdd(&g_score[b * Ln + j0], gcol[j0] * Mcol[j0]);
    atomicAdd(&g_score[b * Ln + j1], gcol[j1] * Mcol[j1]);
  }
}

// ---------------------------------------------------------------------------
// Kernel B (+ inline topk_g): one block per (b, h) = 96 blocks.
// ---------------------------------------------------------------------------
__global__ __launch_bounds__(256, 4) void pairB_kernel(
    const unsigned short* __restrict__ tbf, const float* __restrict__ mask,
    const float* __restrict__ g_score, int* __restrict__ g_top,
    float* __restrict__ loc_rows) {
  const int b = blockIdx.x & 7;
  const int h = blockIdx.x >> 3;
  const int tid = threadIdx.x;
  const int w = tid >> 6, lane = tid & 63;
  const int lr = lane & 15, lg = lane >> 4;
  const int cw = w * 128;

  __shared__ int gidx[32];
  __shared__ float mrow_s[32];
  __shared__ float rscale_s[32];
  __shared__ float redsum[4][32];
  __shared__ float McolB[Ln];
  __shared__ unsigned short es[32][Ln + 8];

  for (int j = tid; j < Ln; j += 256) McolB[j] = mask[b * Ln + j];
  if (w == 1 && lane < 32 - K1n) gidx[K1n + lane] = 0;
  if (w == 0) {
    // single-wave register top-k over g_score[b] (tie -> lowest index)
    float v[8];
    #pragma unroll
    for (int q = 0; q < 8; ++q) v[q] = g_score[b * Ln + q * 64 + lane];
    for (int r = 0; r < K1n; ++r) {
      float bv = v[0]; int bq = 0;
      #pragma unroll
      for (int q = 1; q < 8; ++q) if (v[q] > bv) { bv = v[q]; bq = q; }
      int bj = bq * 64 + lane;
      #pragma unroll
      for (int o = 1; o < 64; o <<= 1) {
        float ov = __shfl_xor(bv, o, 64);
        int oj = __shfl_xor(bj, o, 64);
        if (ov > bv || (ov == bv && oj < bj)) { bv = ov; bj = oj; }
      }
      if (lane == 0) {
        gidx[r] = bj;
        if (h == 0) g_top[b * K1n + r] = bj;
      }
      const int wq = bj >> 6, wl = bj & 63;
      #pragma unroll
      for (int q = 0; q < 8; ++q)
        if (q == wq && lane == wl) v[q] = -3.0e38f;
    }
  }
  __syncthreads();
  if (tid < 32) mrow_s[tid] = (tid < K1n) ? McolB[gidx[tid]] : 0.0f;
  __syncthreads();

  const size_t hb = (size_t)(b * NHn + h) * Ln;
  bf16x8 ta[2][2];
  #pragma unroll
  for (int rt = 0; rt < 2; ++rt) {
    const unsigned short* p = tbf + (hb + gidx[rt * 16 + lr]) * DHn + lg * 8;
    ta[rt][0] = *(const bf16x8*)p;
    ta[rt][1] = *(const bf16x8*)(p + 32);
  }
  const f32x4 zero4 = {0.0f, 0.0f, 0.0f, 0.0f};
  float rsum[2][4] = {{0, 0, 0, 0}, {0, 0, 0, 0}};
  #pragma unroll 1
  for (int ct = 0; ct < 8; ++ct) {
    const int j0 = cw + ct * 16;
    const unsigned short* pb = tbf + (hb + j0 + lr) * DHn + lg * 8;
    bf16x8 tb0 = *(const bf16x8*)pb;
    bf16x8 tb1 = *(const bf16x8*)(pb + 32);
    const float mj = McolB[j0 + lr];
    #pragma unroll
    for (int rt = 0; rt < 2; ++rt) {
      f32x4 tacc = __builtin_amdgcn_mfma_f32_16x16x32_bf16(ta[rt][0], tb0, zero4, 0, 0, 0);
      tacc = __builtin_amdgcn_mfma_f32_16x16x32_bf16(ta[rt][1], tb1, tacc, 0, 0, 0);
      #pragma unroll
      for (int q = 0; q < 4; ++q) {
        const int ri = rt * 16 + lg * 4 + q;
        const float mm = mrow_s[ri] * mj;
        const float st = tacc[q] * 0.125f * mm;
        const float e = __expf(st + (1.0f - mm) * (-10000.0f));
        rsum[rt][q] += e;
        es[ri][j0 + lr] = f2bf(e);
      }
    }
  }
  #pragma unroll
  for (int o = 1; o < 16; o <<= 1) {
    #pragma unroll
    for (int rt = 0; rt < 2; ++rt)
      #pragma unroll
      for (int q = 0; q < 4; ++q) rsum[rt][q] += __shfl_xor(rsum[rt][q], o, 64);
  }
  if (lr == 0) {
    #pragma unroll
    for (int rt = 0; rt < 2; ++rt)
      #pragma unroll
      for (int q = 0; q < 4; ++q) redsum[w][rt * 16 + lg * 4 + q] = rsum[rt][q];
  }
  __syncthreads();
  if (tid < 32) {
    const float fs = redsum[0][tid] + redsum[1][tid] + redsum[2][tid] + redsum[3][tid];
    rscale_s[tid] = mrow_s[tid] / fmaxf(fs, 1e-30f);
  }
  __syncthreads();
  for (int idx = tid; idx < K1n * Ln; idx += 256) {
    const int ri = idx >> 9, j = idx & (Ln - 1);
    const float e = bf2f(es[ri][j]);
    atomicAdd(&loc_rows[(size_t)(b * K1n + ri) * Ln + j], e * rscale_s[ri] * McolB[j]);
  }
}

// ---------------------------------------------------------------------------
// Triplet (+ inline topk_l, + last-block finalize). One block per (b, i1).
// ---------------------------------------------------------------------------
#define TP (Dn + 16)

__global__ __launch_bounds__(256, 1) void triplet_kernel(
    const float* __restrict__ s_rep, const float* __restrict__ t_rep,
    const float* __restrict__ mask, const int* __restrict__ g_top,
    const float* __restrict__ loc_rows, double* __restrict__ acc,
    unsigned int* __restrict__ done_cnt, float* __restrict__ out) {
  const int blk = blockIdx.x, tid = threadIdx.x;
  const int b = blk / K1n, i1 = blk % K1n;
  const int w = tid >> 6, lane = tid & 63;
  const int lr = lane & 15, lg = lane >> 4;

  __shared__ unsigned short NS[32][TP];
  __shared__ unsigned short NT[32][TP];
  __shared__ int lidx[K2n];
  __shared__ float fl2[K2n];
  __shared__ float sred[4], cred[4];
  __shared__ int is_last;
  __shared__ float red[4];

  const int g = g_top[b * K1n + i1];
  if (w == 0) {
    const float* r0 = loc_rows + (size_t)(b * K1n + i1) * Ln;
    float v[8];
    #pragma unroll
    for (int q = 0; q < 8; ++q) {
      const int j = q * 64 + lane;
      v[q] = (j == g) ? 0.0f : r0[j];
    }
    for (int r = 0; r < K2n; ++r) {
      float bv = v[0]; int bq = 0;
      #pragma unroll
      for (int q = 1; q < 8; ++q) if (v[q] > bv) { bv = v[q]; bq = q; }
      int bj = bq * 64 + lane;
      #pragma unroll
      for (int o = 1; o < 64; o <<= 1) {
        float ov = __shfl_xor(bv, o, 64);
        int oj = __shfl_xor(bj, o, 64);
        if (ov > bv || (ov == bv && oj < bj)) { bv = ov; bj = oj; }
      }
      if (lane == 0) lidx[r] = bj;
      const int wq = bj >> 6, wl = bj & 63;
      #pragma unroll
      for (int q = 0; q < 8; ++q)
        if (q == wq && lane == wl) v[q] = -3.0e38f;
    }
  }
  __syncthreads();
  if (tid < K2n)
    fl2[tid] = (mask[b * Ln + g] + mask[b * Ln + lidx[tid]] == 2.0f) ? 1.0f : 0.0f;
  __syncthreads();

  const float* pgs = s_rep + (size_t)(b * Ln + g) * Dn;
  const float* pgt = t_rep + (size_t)(b * Ln + g) * Dn;
  for (int j = w; j < K2n; j += 4) {
    const float* pls = s_rep + (size_t)(b * Ln + lidx[j]) * Dn;
    const float* plt = t_rep + (size_t)(b * Ln + lidx[j]) * Dn;
    float4 ds[3], dt[3];
    float ssq = 0.0f, tsq = 0.0f;
    #pragma unroll
    for (int q = 0; q < 3; ++q) {
      const int c = lane * 4 + q * 256;
      float4 a = *(const float4*)&pgs[c];
      float4 x = *(const float4*)&pls[c];
      ds[q] = make_float4(a.x - x.x, a.y - x.y, a.z - x.z, a.w - x.w);
      ssq += ds[q].x * ds[q].x + ds[q].y * ds[q].y + ds[q].z * ds[q].z + ds[q].w * ds[q].w;
      float4 c2 = *(const float4*)&pgt[c];
      float4 y = *(const float4*)&plt[c];
      dt[q] = make_float4(c2.x - y.x, c2.y - y.y, c2.z - y.z, c2.w - y.w);
      tsq += dt[q].x * dt[q].x + dt[q].y * dt[q].y + dt[q].z * dt[q].z + dt[q].w * dt[q].w;
    }
    #pragma unroll
    for (int o = 1; o < 64; o <<= 1) {
      ssq += __shfl_xor(ssq, o, 64);
      tsq += __shfl_xor(tsq, o, 64);
    }
    const float sinv = 1.0f / fmaxf(sqrtf(ssq), 1e-12f);
    const float tinv = 1.0f / fmaxf(sqrtf(tsq), 1e-12f);
    #pragma unroll
    for (int q = 0; q < 3; ++q) {
      const int c = lane * 4 + q * 256;
      ushort4 us, ut;
      us.x = f2bf(ds[q].x * sinv); us.y = f2bf(ds[q].y * sinv);
      us.z = f2bf(ds[q].z * sinv); us.w = f2bf(ds[q].w * sinv);
      ut.x = f2bf(dt[q].x * tinv); ut.y = f2bf(dt[q].y * tinv);
      ut.z = f2bf(dt[q].z * tinv); ut.w = f2bf(dt[q].w * tinv);
      *(ushort4*)&NS[j][c] = us;
      *(ushort4*)&NT[j][c] = ut;
    }
  }
  __syncthreads();

  const int qr = w >> 1, qc = w & 1;
  f32x4 sacc = {0.0f, 0.0f, 0.0f, 0.0f};
  f32x4 tacc = {0.0f, 0.0f, 0.0f, 0.0f};
  #pragma unroll
  for (int ks = 0; ks < 24; ++ks) {
    const int kk = ks * 32 + lg * 8;
    bf16x8 as = *(const bf16x8*)&NS[qr * 16 + lr][kk];
    bf16x8 bs = *(const bf16x8*)&NS[qc * 16 + lr][kk];
    bf16x8 at = *(const bf16x8*)&NT[qr * 16 + lr][kk];
    bf16x8 bt = *(const bf16x8*)&NT[qc * 16 + lr][kk];
    sacc = __builtin_amdgcn_mfma_f32_16x16x32_bf16(as, bs, sacc, 0, 0, 0);
    tacc = __builtin_amdgcn_mfma_f32_16x16x32_bf16(at, bt, tacc, 0, 0, 0);
  }
  float psum = 0.0f, pcnt = 0.0f;
  #pragma unroll
  for (int q = 0; q < 4; ++q) {
    const int j2 = qr * 16 + lg * 4 + q;
    const int k2 = qc * 16 + lr;
    if (j2 < K2n && k2 < K2n && j2 != k2) {
      const float am = fl2[j2] * fl2[k2];
      const bool smv = (am != 0.0f) && (sacc[q] != 0.0f);
      const bool tmv = (am != 0.0f) && (tacc[q] != 0.0f);
      const float sv = smv ? sacc[q] : 0.0f;
      const float tv = tmv ? tacc[q] : 0.0f;
      const float d = sv - tv;
      const float ad = fabsf(d);
      psum += (ad < 1.0f) ? 0.5f * d * d : (ad - 0.5f);
      pcnt += smv ? 1.0f : 0.0f;
    }
  }
  #pragma unroll
  for (int o = 1; o < 64; o <<= 1) {
    psum += __shfl_xor(psum, o, 64);
    pcnt += __shfl_xor(pcnt, o, 64);
  }
  if (lane == 0) { sred[w] = psum; cred[w] = pcnt; }
  __syncthreads();
  if (tid == 0) {
    atomicAdd(&acc[1], (double)(sred[0] + sred[1] + sred[2] + sred[3]));
    atomicAdd(&acc[2], (double)(cred[0] + cred[1] + cred[2] + cred[3]));
    __threadfence();
    const unsigned int done = atomicAdd(done_cnt, 1u);
    is_last = (done == (unsigned int)(Bn * K1n - 1)) ? 1 : 0;
  }
  __syncthreads();

  if (is_last) {
    double sm = 0.0;
    for (int bb = 0; bb < Bn; ++bb) {
      float p = 0.0f;
      for (int i = tid; i < Ln; i += 256) p += mask[bb * Ln + i];
      #pragma unroll
      for (int o = 1; o < 64; o <<= 1) p += __shfl_xor(p, o, 64);
      __syncthreads();
      if ((tid & 63) == 0) red[tid >> 6] = p;
      __syncthreads();
      if (tid == 0) {
        float rs = red[0] + red[1] + red[2] + red[3];
        sm += (double)rs * (double)rs;
      }
    }
    __syncthreads();
    if (tid == 0) {
      const double a0 = atomicAdd(&acc[0], 0.0);
      const double a1 = atomicAdd(&acc[1], 0.0);
      const double a2 = atomicAdd(&acc[2], 0.0);
      const double lp = a0 / ((double)NHn * sm);
      const double lt = a1 / a2;
      out[0] = (float)(lp + lt);
    }
  }
}

// ---------------------------------------------------------------------------
extern "C" void kernel_launch(void* const* d_in, const int* in_sizes, int n_in,
                              void* d_out, int out_size, void* d_ws, size_t ws_size,
                              hipStream_t stream) {
  const float* s_rep = (const float*)d_in[0];
  const float* t_rep = (const float*)d_in[1];
  const float* mask  = (const float*)d_in[2];
  float* out = (float*)d_out;

  char* w = (char*)d_ws;
  double* acc      = (double*)(w + WS_ACC);
  unsigned int* done_cnt = (unsigned int*)(w + WS_ACC + 48);
  float* g_score   = (float*)(w + WS_GSCORE);
  float* loc_rows  = (float*)(w + WS_LOCR);
  int* g_top       = (int*)(w + WS_GTOP);
  unsigned short* sbf = (unsigned short*)(w + WS_SBF);
  unsigned short* tbf = (unsigned short*)(w + WS_TBF);

  hipMemsetAsync(d_ws, 0, WS_ZERO_BYTES, stream);

  prep_bf16_kernel<<<Bn * Ln * Dn / 4 / 256, 256, 0, stream>>>(s_rep, t_rep, sbf, tbf);
  pairA_kernel<<<Bn * NHn * (Ln / 32), 256, 0, stream>>>(sbf, tbf, mask, g_score, acc);
  pairB_kernel<<<Bn * NHn, 256, 0, stream>>>(tbf, mask, g_score, g_top, loc_rows);
  triplet_kernel<<<Bn * K1n, 256, 0, stream>>>(s_rep, t_rep, mask, g_top, loc_rows,
                                               acc, done_cnt, out);
}

// Round 11
// 108.361 us; speedup vs baseline: 1.5975x; 1.1677x over previous
//
#include <hip/hip_runtime.h>
#include <hip/hip_bf16.h>
#include <math.h>

#define Bn 8
#define Ln 512
#define Dn 768
#define NHn 12
#define DHn 64
#define K1n 20
#define K2n 20
#define BST 72    // LDS B-tile row stride in shorts
#define TROWS 64  // B-tile rows per stage

// workspace layout (bytes)
#define WS_ACC    0          // double acc[8]; bytes 48..51 = done-counter
#define WS_GSCORE 64         // float g_score[8*512]
#define WS_LOCR   16448      // float loc_rows[8*20*512] (320 KB)
#define WS_GTOP   344128     // int g_top[8*20]
#define WS_SBF    357568     // ushort sbf[8*12*512*64] bf16 head-major
#define WS_TBF    6649024    // ushort tbf[...] (ends 12940480)
#define WS_ZERO_BYTES 344128 // acc + counter + g_score + loc_rows

typedef __attribute__((ext_vector_type(8))) short bf16x8;
typedef __attribute__((ext_vector_type(4))) float f32x4;

__device__ inline unsigned short f2bf(float x) {
  __hip_bfloat16 h = __float2bfloat16(x);
  return *reinterpret_cast<unsigned short*>(&h);
}
__device__ inline float bf2f(unsigned short u) {
  return __uint_as_float(((unsigned int)u) << 16);
}

// ---------------------------------------------------------------------------
// Prep: fp32 [b][row][h*64+k] -> bf16 head-major [b][h][row][k]
// ---------------------------------------------------------------------------
__global__ __launch_bounds__(256) void prep_bf16_kernel(
    const float* __restrict__ s, const float* __restrict__ t,
    unsigned short* __restrict__ sbf, unsigned short* __restrict__ tbf) {
  int gid = blockIdx.x * 256 + threadIdx.x;
  int f = gid * 4;
  int col = f % Dn;
  int rb = f / Dn;
  int row = rb & (Ln - 1);
  int b = rb >> 9;
  int h = col >> 6;
  int k = col & 63;
  size_t dst = (((size_t)(b * NHn + h) * Ln + row) * DHn + k);
  float4 vs = *(const float4*)(s + f);
  float4 vt = *(const float4*)(t + f);
  ushort4 us, ut;
  us.x = f2bf(vs.x); us.y = f2bf(vs.y); us.z = f2bf(vs.z); us.w = f2bf(vs.w);
  ut.x = f2bf(vt.x); ut.y = f2bf(vt.y); ut.z = f2bf(vt.z); ut.w = f2bf(vt.w);
  *(ushort4*)(sbf + dst) = us;
  *(ushort4*)(tbf + dst) = ut;
}

// ---------------------------------------------------------------------------
// Kernel A v4: software-pipelined LDS staging. One block per (b, h, 64-row
// tile) -> grid 768, all co-resident (3 blocks/CU @ 41 KB LDS). Each wave
// owns 16 rows x all 512 cols -> row sums are wave-local (no LDS exchange).
// Per tile: issue next tile's global loads -> compute current (MFMA hides
// L2 latency) -> vmcnt -> ds_write next buffer -> ONE barrier.  Round 10's
// stage/drain/barrier/compute serial cadence left ~60% stall.
// Two-pass recompute for softmax (pass 2 re-stages t only, same pipeline).
// ---------------------------------------------------------------------------
__global__ __launch_bounds__(256) void pairA_kernel(
    const unsigned short* __restrict__ sbf, const unsigned short* __restrict__ tbf,
    const float* __restrict__ mask, float* __restrict__ g_score,
    double* __restrict__ acc) {
  const int b = blockIdx.x & 7;
  const int r = blockIdx.x >> 3;          // 0..95
  const int it = r / NHn;                 // 0..7
  const int h = r - it * NHn;             // 0..11
  const int tid = threadIdx.x;
  const int w = tid >> 6;                 // wave: rows [it*64 + w*16, +16)
  const int lane = tid & 63;
  const int lr = lane & 15, lg = lane >> 4;

  __shared__ unsigned short Bs[2][TROWS * BST];
  __shared__ unsigned short Bt[2][TROWS * BST];
  __shared__ float Mcol[Ln];
  __shared__ float gcol[Ln];
  __shared__ float wred[4];

  // staging slots: 512 bf16x8 slots per (s|t) tile, 2 per thread
  const int s_r0 = tid >> 3;              // 0..31
  const int s_r1 = s_r0 + 32;             // 32..63
  const int s_c = (tid & 7) * 8;

  for (int j = tid; j < Ln; j += 256) {
    Mcol[j] = mask[b * Ln + j];
    gcol[j] = 0.0f;
  }

  const size_t hb = (size_t)(b * NHn + h) * Ln;
  const int rw = it * 64 + w * 16;
  // A fragments (one-time gather)
  const unsigned short* pas = sbf + (hb + rw + lr) * DHn + lg * 8;
  const unsigned short* pat = tbf + (hb + rw + lr) * DHn + lg * 8;
  bf16x8 sa0 = *(const bf16x8*)pas;
  bf16x8 sa1 = *(const bf16x8*)(pas + 32);
  bf16x8 ta0 = *(const bf16x8*)pat;
  bf16x8 ta1 = *(const bf16x8*)(pat + 32);

  // prologue: stage tile 0 into buffer 0
  {
    bf16x8 v0 = *(const bf16x8*)(sbf + (hb + s_r0) * DHn + s_c);
    bf16x8 v1 = *(const bf16x8*)(sbf + (hb + s_r1) * DHn + s_c);
    bf16x8 u0 = *(const bf16x8*)(tbf + (hb + s_r0) * DHn + s_c);
    bf16x8 u1 = *(const bf16x8*)(tbf + (hb + s_r1) * DHn + s_c);
    *(bf16x8*)&Bs[0][s_r0 * BST + s_c] = v0;
    *(bf16x8*)&Bs[0][s_r1 * BST + s_c] = v1;
    *(bf16x8*)&Bt[0][s_r0 * BST + s_c] = u0;
    *(bf16x8*)&Bt[0][s_r1 * BST + s_c] = u1;
  }
  __syncthreads();

  float mrow[4];
  #pragma unroll
  for (int q = 0; q < 4; ++q) mrow[q] = Mcol[rw + lg * 4 + q];

  const f32x4 zero4 = {0.0f, 0.0f, 0.0f, 0.0f};
  float lpair = 0.0f;
  float rsum[4] = {0.0f, 0.0f, 0.0f, 0.0f};

  // ---- pass 1: diff^2 + row sums (pipelined over 8 tiles) ----
  #pragma unroll 1
  for (int t = 0; t < 8; ++t) {
    const int cur = t & 1;
    // issue next tile's loads FIRST (latency hides under compute below)
    bf16x8 v0, v1, u0, u1;
    if (t < 7) {
      const int jn = (t + 1) * TROWS;
      v0 = *(const bf16x8*)(sbf + (hb + jn + s_r0) * DHn + s_c);
      v1 = *(const bf16x8*)(sbf + (hb + jn + s_r1) * DHn + s_c);
      u0 = *(const bf16x8*)(tbf + (hb + jn + s_r0) * DHn + s_c);
      u1 = *(const bf16x8*)(tbf + (hb + jn + s_r1) * DHn + s_c);
    }
    // compute current tile: 4 col-groups of 16
    #pragma unroll
    for (int c = 0; c < 4; ++c) {
      const int jl = c * 16;
      const int j0 = t * TROWS + jl;
      const unsigned short* pbs = &Bs[cur][(jl + lr) * BST + lg * 8];
      const unsigned short* pbt = &Bt[cur][(jl + lr) * BST + lg * 8];
      bf16x8 sb0 = *(const bf16x8*)pbs;
      bf16x8 sb1 = *(const bf16x8*)(pbs + 32);
      bf16x8 tb0 = *(const bf16x8*)pbt;
      bf16x8 tb1 = *(const bf16x8*)(pbt + 32);
      f32x4 sacc = __builtin_amdgcn_mfma_f32_16x16x32_bf16(sa0, sb0, zero4, 0, 0, 0);
      sacc = __builtin_amdgcn_mfma_f32_16x16x32_bf16(sa1, sb1, sacc, 0, 0, 0);
      f32x4 tacc = __builtin_amdgcn_mfma_f32_16x16x32_bf16(ta0, tb0, zero4, 0, 0, 0);
      tacc = __builtin_amdgcn_mfma_f32_16x16x32_bf16(ta1, tb1, tacc, 0, 0, 0);
      const float mj = Mcol[j0 + lr];
      #pragma unroll
      for (int q = 0; q < 4; ++q) {
        const float mm = mrow[q] * mj;
        const float ss = sacc[q] * 0.125f * mm;
        const float st = tacc[q] * 0.125f * mm;
        const float d = ss - st;
        lpair += d * d;
        rsum[q] += __expf(st + (1.0f - mm) * (-10000.0f));
      }
    }
    // write next buffer (vmcnt wait folds here), single barrier per tile
    if (t < 7) {
      const int nxt = cur ^ 1;
      *(bf16x8*)&Bs[nxt][s_r0 * BST + s_c] = v0;
      *(bf16x8*)&Bs[nxt][s_r1 * BST + s_c] = v1;
      *(bf16x8*)&Bt[nxt][s_r0 * BST + s_c] = u0;
      *(bf16x8*)&Bt[nxt][s_r1 * BST + s_c] = u1;
    }
    __syncthreads();
  }

  // row sums are wave-local: reduce across the 16 lr lanes only
  #pragma unroll
  for (int o = 1; o < 16; o <<= 1) {
    #pragma unroll
    for (int q = 0; q < 4; ++q) rsum[q] += __shfl_xor(rsum[q], o, 64);
  }
  float rscale[4];
  #pragma unroll
  for (int q = 0; q < 4; ++q)
    rscale[q] = mrow[q] / fmaxf(rsum[q], 1e-30f);

  // ---- pass 2: recompute e (t only), scale, column sums (pipelined) ----
  {
    bf16x8 u0 = *(const bf16x8*)(tbf + (hb + s_r0) * DHn + s_c);
    bf16x8 u1 = *(const bf16x8*)(tbf + (hb + s_r1) * DHn + s_c);
    *(bf16x8*)&Bt[0][s_r0 * BST + s_c] = u0;
    *(bf16x8*)&Bt[0][s_r1 * BST + s_c] = u1;
  }
  __syncthreads();

  #pragma unroll 1
  for (int t = 0; t < 8; ++t) {
    const int cur = t & 1;
    bf16x8 u0, u1;
    if (t < 7) {
      const int jn = (t + 1) * TROWS;
      u0 = *(const bf16x8*)(tbf + (hb + jn + s_r0) * DHn + s_c);
      u1 = *(const bf16x8*)(tbf + (hb + jn + s_r1) * DHn + s_c);
    }
    #pragma unroll
    for (int c = 0; c < 4; ++c) {
      const int jl = c * 16;
      const int j0 = t * TROWS + jl;
      const unsigned short* pbt = &Bt[cur][(jl + lr) * BST + lg * 8];
      bf16x8 tb0 = *(const bf16x8*)pbt;
      bf16x8 tb1 = *(const bf16x8*)(pbt + 32);
      f32x4 tacc = __builtin_amdgcn_mfma_f32_16x16x32_bf16(ta0, tb0, zero4, 0, 0, 0);
      tacc = __builtin_amdgcn_mfma_f32_16x16x32_bf16(ta1, tb1, tacc, 0, 0, 0);
      const float mj = Mcol[j0 + lr];
      float pc = 0.0f;
      #pragma unroll
      for (int q = 0; q < 4; ++q) {
        const float mm = mrow[q] * mj;
        const float st = tacc[q] * 0.125f * mm;
        const float e = __expf(st + (1.0f - mm) * (-10000.0f));
        pc += e * rscale[q];
      }
      pc += __shfl_xor(pc, 16, 64);
      pc += __shfl_xor(pc, 32, 64);
      if (lg == 0) atomicAdd(&gcol[j0 + lr], pc);
    }
    if (t < 7) {
      const int nxt = cur ^ 1;
      *(bf16x8*)&Bt[nxt][s_r0 * BST + s_c] = u0;
      *(bf16x8*)&Bt[nxt][s_r1 * BST + s_c] = u1;
    }
    __syncthreads();
  }

  // pair-loss partial
  #pragma unroll
  for (int o = 1; o < 64; o <<= 1) lpair += __shfl_xor(lpair, o, 64);
  if (lane == 0) wred[w] = lpair;
  __syncthreads();

  if (tid == 0) {
    atomicAdd(&acc[0], (double)((wred[0] + wred[1]) + (wred[2] + wred[3])));
  }
  {
    const int j0 = tid, j1 = tid + 256;
    atomicAdd(&g_score[b * Ln + j0], gcol[j0] * Mcol[j0]);
    atomicAdd(&g_score[b * Ln + j1], gcol[j1] * Mcol[j1]);
  }
}

// ---------------------------------------------------------------------------
// Kernel B (+ inline topk_g): one block per (b, h) = 96 blocks.
// ---------------------------------------------------------------------------
__global__ __launch_bounds__(256, 4) void pairB_kernel(
    const unsigned short* __restrict__ tbf, const float* __restrict__ mask,
    const float* __restrict__ g_score, int* __restrict__ g_top,
    float* __restrict__ loc_rows) {
  const int b = blockIdx.x & 7;
  const int h = blockIdx.x >> 3;
  const int tid = threadIdx.x;
  const int w = tid >> 6, lane = tid & 63;
  const int lr = lane & 15, lg = lane >> 4;
  const int cw = w * 128;

  __shared__ int gidx[32];
  __shared__ float mrow_s[32];
  __shared__ float rscale_s[32];
  __shared__ float redsum[4][32];
  __shared__ float McolB[Ln];
  __shared__ unsigned short es[32][Ln + 8];

  for (int j = tid; j < Ln; j += 256) McolB[j] = mask[b * Ln + j];
  if (w == 1 && lane < 32 - K1n) gidx[K1n + lane] = 0;
  if (w == 0) {
    float v[8];
    #pragma unroll
    for (int q = 0; q < 8; ++q) v[q] = g_score[b * Ln + q * 64 + lane];
    for (int r = 0; r < K1n; ++r) {
      float bv = v[0]; int bq = 0;
      #pragma unroll
      for (int q = 1; q < 8; ++q) if (v[q] > bv) { bv = v[q]; bq = q; }
      int bj = bq * 64 + lane;
      #pragma unroll
      for (int o = 1; o < 64; o <<= 1) {
        float ov = __shfl_xor(bv, o, 64);
        int oj = __shfl_xor(bj, o, 64);
        if (ov > bv || (ov == bv && oj < bj)) { bv = ov; bj = oj; }
      }
      if (lane == 0) {
        gidx[r] = bj;
        if (h == 0) g_top[b * K1n + r] = bj;
      }
      const int wq = bj >> 6, wl = bj & 63;
      #pragma unroll
      for (int q = 0; q < 8; ++q)
        if (q == wq && lane == wl) v[q] = -3.0e38f;
    }
  }
  __syncthreads();
  if (tid < 32) mrow_s[tid] = (tid < K1n) ? McolB[gidx[tid]] : 0.0f;
  __syncthreads();

  const size_t hb = (size_t)(b * NHn + h) * Ln;
  bf16x8 ta[2][2];
  #pragma unroll
  for (int rt = 0; rt < 2; ++rt) {
    const unsigned short* p = tbf + (hb + gidx[rt * 16 + lr]) * DHn + lg * 8;
    ta[rt][0] = *(const bf16x8*)p;
    ta[rt][1] = *(const bf16x8*)(p + 32);
  }
  const f32x4 zero4 = {0.0f, 0.0f, 0.0f, 0.0f};
  float rsum[2][4] = {{0, 0, 0, 0}, {0, 0, 0, 0}};
  #pragma unroll 1
  for (int ct = 0; ct < 8; ++ct) {
    const int j0 = cw + ct * 16;
    const unsigned short* pb = tbf + (hb + j0 + lr) * DHn + lg * 8;
    bf16x8 tb0 = *(const bf16x8*)pb;
    bf16x8 tb1 = *(const bf16x8*)(pb + 32);
    const float mj = McolB[j0 + lr];
    #pragma unroll
    for (int rt = 0; rt < 2; ++rt) {
      f32x4 tacc = __builtin_amdgcn_mfma_f32_16x16x32_bf16(ta[rt][0], tb0, zero4, 0, 0, 0);
      tacc = __builtin_amdgcn_mfma_f32_16x16x32_bf16(ta[rt][1], tb1, tacc, 0, 0, 0);
      #pragma unroll
      for (int q = 0; q < 4; ++q) {
        const int ri = rt * 16 + lg * 4 + q;
        const float mm = mrow_s[ri] * mj;
        const float st = tacc[q] * 0.125f * mm;
        const float e = __expf(st + (1.0f - mm) * (-10000.0f));
        rsum[rt][q] += e;
        es[ri][j0 + lr] = f2bf(e);
      }
    }
  }
  #pragma unroll
  for (int o = 1; o < 16; o <<= 1) {
    #pragma unroll
    for (int rt = 0; rt < 2; ++rt)
      #pragma unroll
      for (int q = 0; q < 4; ++q) rsum[rt][q] += __shfl_xor(rsum[rt][q], o, 64);
  }
  if (lr == 0) {
    #pragma unroll
    for (int rt = 0; rt < 2; ++rt)
      #pragma unroll
      for (int q = 0; q < 4; ++q) redsum[w][rt * 16 + lg * 4 + q] = rsum[rt][q];
  }
  __syncthreads();
  if (tid < 32) {
    const float fs = redsum[0][tid] + redsum[1][tid] + redsum[2][tid] + redsum[3][tid];
    rscale_s[tid] = mrow_s[tid] / fmaxf(fs, 1e-30f);
  }
  __syncthreads();
  for (int idx = tid; idx < K1n * Ln; idx += 256) {
    const int ri = idx >> 9, j = idx & (Ln - 1);
    const float e = bf2f(es[ri][j]);
    atomicAdd(&loc_rows[(size_t)(b * K1n + ri) * Ln + j], e * rscale_s[ri] * McolB[j]);
  }
}

// ---------------------------------------------------------------------------
// Triplet (+ inline topk_l, + last-block finalize). One block per (b, i1).
// ---------------------------------------------------------------------------
#define TP (Dn + 16)

__global__ __launch_bounds__(256, 1) void triplet_kernel(
    const float* __restrict__ s_rep, const float* __restrict__ t_rep,
    const float* __restrict__ mask, const int* __restrict__ g_top,
    const float* __restrict__ loc_rows, double* __restrict__ acc,
    unsigned int* __restrict__ done_cnt, float* __restrict__ out) {
  const int blk = blockIdx.x, tid = threadIdx.x;
  const int b = blk / K1n, i1 = blk % K1n;
  const int w = tid >> 6, lane = tid & 63;
  const int lr = lane & 15, lg = lane >> 4;

  __shared__ unsigned short NS[32][TP];
  __shared__ unsigned short NT[32][TP];
  __shared__ int lidx[K2n];
  __shared__ float fl2[K2n];
  __shared__ float sred[4], cred[4];
  __shared__ int is_last;
  __shared__ float red[4];

  const int g = g_top[b * K1n + i1];
  if (w == 0) {
    const float* r0 = loc_rows + (size_t)(b * K1n + i1) * Ln;
    float v[8];
    #pragma unroll
    for (int q = 0; q < 8; ++q) {
      const int j = q * 64 + lane;
      v[q] = (j == g) ? 0.0f : r0[j];
    }
    for (int r = 0; r < K2n; ++r) {
      float bv = v[0]; int bq = 0;
      #pragma unroll
      for (int q = 1; q < 8; ++q) if (v[q] > bv) { bv = v[q]; bq = q; }
      int bj = bq * 64 + lane;
      #pragma unroll
      for (int o = 1; o < 64; o <<= 1) {
        float ov = __shfl_xor(bv, o, 64);
        int oj = __shfl_xor(bj, o, 64);
        if (ov > bv || (ov == bv && oj < bj)) { bv = ov; bj = oj; }
      }
      if (lane == 0) lidx[r] = bj;
      const int wq = bj >> 6, wl = bj & 63;
      #pragma unroll
      for (int q = 0; q < 8; ++q)
        if (q == wq && lane == wl) v[q] = -3.0e38f;
    }
  }
  __syncthreads();
  if (tid < K2n)
    fl2[tid] = (mask[b * Ln + g] + mask[b * Ln + lidx[tid]] == 2.0f) ? 1.0f : 0.0f;
  __syncthreads();

  const float* pgs = s_rep + (size_t)(b * Ln + g) * Dn;
  const float* pgt = t_rep + (size_t)(b * Ln + g) * Dn;
  for (int j = w; j < K2n; j += 4) {
    const float* pls = s_rep + (size_t)(b * Ln + lidx[j]) * Dn;
    const float* plt = t_rep + (size_t)(b * Ln + lidx[j]) * Dn;
    float4 ds[3], dt[3];
    float ssq = 0.0f, tsq = 0.0f;
    #pragma unroll
    for (int q = 0; q < 3; ++q) {
      const int c = lane * 4 + q * 256;
      float4 a = *(const float4*)&pgs[c];
      float4 x = *(const float4*)&pls[c];
      ds[q] = make_float4(a.x - x.x, a.y - x.y, a.z - x.z, a.w - x.w);
      ssq += ds[q].x * ds[q].x + ds[q].y * ds[q].y + ds[q].z * ds[q].z + ds[q].w * ds[q].w;
      float4 c2 = *(const float4*)&pgt[c];
      float4 y = *(const float4*)&plt[c];
      dt[q] = make_float4(c2.x - y.x, c2.y - y.y, c2.z - y.z, c2.w - y.w);
      tsq += dt[q].x * dt[q].x + dt[q].y * dt[q].y + dt[q].z * dt[q].z + dt[q].w * dt[q].w;
    }
    #pragma unroll
    for (int o = 1; o < 64; o <<= 1) {
      ssq += __shfl_xor(ssq, o, 64);
      tsq += __shfl_xor(tsq, o, 64);
    }
    const float sinv = 1.0f / fmaxf(sqrtf(ssq), 1e-12f);
    const float tinv = 1.0f / fmaxf(sqrtf(tsq), 1e-12f);
    #pragma unroll
    for (int q = 0; q < 3; ++q) {
      const int c = lane * 4 + q * 256;
      ushort4 us, ut;
      us.x = f2bf(ds[q].x * sinv); us.y = f2bf(ds[q].y * sinv);
      us.z = f2bf(ds[q].z * sinv); us.w = f2bf(ds[q].w * sinv);
      ut.x = f2bf(dt[q].x * tinv); ut.y = f2bf(dt[q].y * tinv);
      ut.z = f2bf(dt[q].z * tinv); ut.w = f2bf(dt[q].w * tinv);
      *(ushort4*)&NS[j][c] = us;
      *(ushort4*)&NT[j][c] = ut;
    }
  }
  __syncthreads();

  const int qr = w >> 1, qc = w & 1;
  f32x4 sacc = {0.0f, 0.0f, 0.0f, 0.0f};
  f32x4 tacc = {0.0f, 0.0f, 0.0f, 0.0f};
  #pragma unroll
  for (int ks = 0; ks < 24; ++ks) {
    const int kk = ks * 32 + lg * 8;
    bf16x8 as = *(const bf16x8*)&NS[qr * 16 + lr][kk];
    bf16x8 bs = *(const bf16x8*)&NS[qc * 16 + lr][kk];
    bf16x8 at = *(const bf16x8*)&NT[qr * 16 + lr][kk];
    bf16x8 bt = *(const bf16x8*)&NT[qc * 16 + lr][kk];
    sacc = __builtin_amdgcn_mfma_f32_16x16x32_bf16(as, bs, sacc, 0, 0, 0);
    tacc = __builtin_amdgcn_mfma_f32_16x16x32_bf16(at, bt, tacc, 0, 0, 0);
  }
  float psum = 0.0f, pcnt = 0.0f;
  #pragma unroll
  for (int q = 0; q < 4; ++q) {
    const int j2 = qr * 16 + lg * 4 + q;
    const int k2 = qc * 16 + lr;
    if (j2 < K2n && k2 < K2n && j2 != k2) {
      const float am = fl2[j2] * fl2[k2];
      const bool smv = (am != 0.0f) && (sacc[q] != 0.0f);
      const bool tmv = (am != 0.0f) && (tacc[q] != 0.0f);
      const float sv = smv ? sacc[q] : 0.0f;
      const float tv = tmv ? tacc[q] : 0.0f;
      const float d = sv - tv;
      const float ad = fabsf(d);
      psum += (ad < 1.0f) ? 0.5f * d * d : (ad - 0.5f);
      pcnt += smv ? 1.0f : 0.0f;
    }
  }
  #pragma unroll
  for (int o = 1; o < 64; o <<= 1) {
    psum += __shfl_xor(psum, o, 64);
    pcnt += __shfl_xor(pcnt, o, 64);
  }
  if (lane == 0) { sred[w] = psum; cred[w] = pcnt; }
  __syncthreads();
  if (tid == 0) {
    atomicAdd(&acc[1], (double)(sred[0] + sred[1] + sred[2] + sred[3]));
    atomicAdd(&acc[2], (double)(cred[0] + cred[1] + cred[2] + cred[3]));
    __threadfence();
    const unsigned int done = atomicAdd(done_cnt, 1u);
    is_last = (done == (unsigned int)(Bn * K1n - 1)) ? 1 : 0;
  }
  __syncthreads();

  if (is_last) {
    double sm = 0.0;
    for (int bb = 0; bb < Bn; ++bb) {
      float p = 0.0f;
      for (int i = tid; i < Ln; i += 256) p += mask[bb * Ln + i];
      #pragma unroll
      for (int o = 1; o < 64; o <<= 1) p += __shfl_xor(p, o, 64);
      __syncthreads();
      if ((tid & 63) == 0) red[tid >> 6] = p;
      __syncthreads();
      if (tid == 0) {
        float rs = red[0] + red[1] + red[2] + red[3];
        sm += (double)rs * (double)rs;
      }
    }
    __syncthreads();
    if (tid == 0) {
      const double a0 = atomicAdd(&acc[0], 0.0);
      const double a1 = atomicAdd(&acc[1], 0.0);
      const double a2 = atomicAdd(&acc[2], 0.0);
      const double lp = a0 / ((double)NHn * sm);
      const double lt = a1 / a2;
      out[0] = (float)(lp + lt);
    }
  }
}

// ---------------------------------------------------------------------------
extern "C" void kernel_launch(void* const* d_in, const int* in_sizes, int n_in,
                              void* d_out, int out_size, void* d_ws, size_t ws_size,
                              hipStream_t stream) {
  const float* s_rep = (const float*)d_in[0];
  const float* t_rep = (const float*)d_in[1];
  const float* mask  = (const float*)d_in[2];
  float* out = (float*)d_out;

  char* w = (char*)d_ws;
  double* acc      = (double*)(w + WS_ACC);
  unsigned int* done_cnt = (unsigned int*)(w + WS_ACC + 48);
  float* g_score   = (float*)(w + WS_GSCORE);
  float* loc_rows  = (float*)(w + WS_LOCR);
  int* g_top       = (int*)(w + WS_GTOP);
  unsigned short* sbf = (unsigned short*)(w + WS_SBF);
  unsigned short* tbf = (unsigned short*)(w + WS_TBF);

  hipMemsetAsync(d_ws, 0, WS_ZERO_BYTES, stream);

  prep_bf16_kernel<<<Bn * Ln * Dn / 4 / 256, 256, 0, stream>>>(s_rep, t_rep, sbf, tbf);
  pairA_kernel<<<Bn * NHn * (Ln / 64), 256, 0, stream>>>(sbf, tbf, mask, g_score, acc);
  pairB_kernel<<<Bn * NHn, 256, 0, stream>>>(tbf, mask, g_score, g_top, loc_rows);
  triplet_kernel<<<Bn * K1n, 256, 0, stream>>>(s_rep, t_rep, mask, g_top, loc_rows,
                                               acc, done_cnt, out);
}

// Round 12
// 103.206 us; speedup vs baseline: 1.6772x; 1.0499x over previous
//
#include <hip/hip_runtime.h>
#include <hip/hip_bf16.h>
#include <math.h>

#define Bn 8
#define Ln 512
#define Dn 768
#define NHn 12
#define DHn 64
#define K1n 20
#define K2n 20
#define BST 72    // LDS B-tile row stride in shorts
#define TROWS 64  // B-tile rows per stage

// workspace layout (bytes) -- NO memset: acc/g_score zeroed by prep block 0,
// loc_part is fully written non-atomically by pairB (no init needed).
#define WS_ACC    0          // double acc[8]; bytes 48..51 = done-counter
#define WS_GSCORE 64         // float g_score[8*512] (16 KB)
#define WS_GTOP   16448      // int g_top[8*20]
#define WS_LOCP   17152      // float loc_part[12][8][20][512] (3.93 MB)
#define WS_SBF    3949312    // ushort sbf[8*12*512*64] bf16 head-major
#define WS_TBF    10240768   // ushort tbf[...] (ends 16532224)

typedef __attribute__((ext_vector_type(8))) short bf16x8;
typedef __attribute__((ext_vector_type(4))) float f32x4;

__device__ inline unsigned short f2bf(float x) {
  __hip_bfloat16 h = __float2bfloat16(x);
  return *reinterpret_cast<unsigned short*>(&h);
}
__device__ inline float bf2f(unsigned short u) {
  return __uint_as_float(((unsigned int)u) << 16);
}

// ---------------------------------------------------------------------------
// Prep: fp32 [b][row][h*64+k] -> bf16 head-major [b][h][row][k].
// Block 0 additionally zeroes acc (64 B incl. done-counter) and g_score
// (16 KB) -- replaces the 42 us rocclr fillBuffer dispatch (round 11 PMC).
// ---------------------------------------------------------------------------
__global__ __launch_bounds__(256) void prep_bf16_kernel(
    const float* __restrict__ s, const float* __restrict__ t,
    unsigned short* __restrict__ sbf, unsigned short* __restrict__ tbf,
    float* __restrict__ g_score, int* __restrict__ accw) {
  int tid = threadIdx.x;
  if (blockIdx.x == 0) {
    if (tid < 16) accw[tid] = 0;                       // acc[0..7] + done
    for (int i = tid; i < Bn * Ln; i += 256) g_score[i] = 0.0f;
  }
  int gid = blockIdx.x * 256 + tid;
  int f = gid * 4;
  int col = f % Dn;
  int rb = f / Dn;
  int row = rb & (Ln - 1);
  int b = rb >> 9;
  int h = col >> 6;
  int k = col & 63;
  size_t dst = (((size_t)(b * NHn + h) * Ln + row) * DHn + k);
  float4 vs = *(const float4*)(s + f);
  float4 vt = *(const float4*)(t + f);
  ushort4 us, ut;
  us.x = f2bf(vs.x); us.y = f2bf(vs.y); us.z = f2bf(vs.z); us.w = f2bf(vs.w);
  ut.x = f2bf(vt.x); ut.y = f2bf(vt.y); ut.z = f2bf(vt.z); ut.w = f2bf(vt.w);
  *(ushort4*)(sbf + dst) = us;
  *(ushort4*)(tbf + dst) = ut;
}

// ---------------------------------------------------------------------------
// Kernel A v4 (unchanged from round 11): software-pipelined LDS staging.
// One block per (b, h, 64-row tile) -> grid 768, 3 blocks/CU @ 41 KB LDS.
// ---------------------------------------------------------------------------
__global__ __launch_bounds__(256) void pairA_kernel(
    const unsigned short* __restrict__ sbf, const unsigned short* __restrict__ tbf,
    const float* __restrict__ mask, float* __restrict__ g_score,
    double* __restrict__ acc) {
  const int b = blockIdx.x & 7;
  const int r = blockIdx.x >> 3;          // 0..95
  const int it = r / NHn;                 // 0..7
  const int h = r - it * NHn;             // 0..11
  const int tid = threadIdx.x;
  const int w = tid >> 6;                 // wave: rows [it*64 + w*16, +16)
  const int lane = tid & 63;
  const int lr = lane & 15, lg = lane >> 4;

  __shared__ unsigned short Bs[2][TROWS * BST];
  __shared__ unsigned short Bt[2][TROWS * BST];
  __shared__ float Mcol[Ln];
  __shared__ float gcol[Ln];
  __shared__ float wred[4];

  const int s_r0 = tid >> 3;              // 0..31
  const int s_r1 = s_r0 + 32;             // 32..63
  const int s_c = (tid & 7) * 8;

  for (int j = tid; j < Ln; j += 256) {
    Mcol[j] = mask[b * Ln + j];
    gcol[j] = 0.0f;
  }

  const size_t hb = (size_t)(b * NHn + h) * Ln;
  const int rw = it * 64 + w * 16;
  const unsigned short* pas = sbf + (hb + rw + lr) * DHn + lg * 8;
  const unsigned short* pat = tbf + (hb + rw + lr) * DHn + lg * 8;
  bf16x8 sa0 = *(const bf16x8*)pas;
  bf16x8 sa1 = *(const bf16x8*)(pas + 32);
  bf16x8 ta0 = *(const bf16x8*)pat;
  bf16x8 ta1 = *(const bf16x8*)(pat + 32);

  {
    bf16x8 v0 = *(const bf16x8*)(sbf + (hb + s_r0) * DHn + s_c);
    bf16x8 v1 = *(const bf16x8*)(sbf + (hb + s_r1) * DHn + s_c);
    bf16x8 u0 = *(const bf16x8*)(tbf + (hb + s_r0) * DHn + s_c);
    bf16x8 u1 = *(const bf16x8*)(tbf + (hb + s_r1) * DHn + s_c);
    *(bf16x8*)&Bs[0][s_r0 * BST + s_c] = v0;
    *(bf16x8*)&Bs[0][s_r1 * BST + s_c] = v1;
    *(bf16x8*)&Bt[0][s_r0 * BST + s_c] = u0;
    *(bf16x8*)&Bt[0][s_r1 * BST + s_c] = u1;
  }
  __syncthreads();

  float mrow[4];
  #pragma unroll
  for (int q = 0; q < 4; ++q) mrow[q] = Mcol[rw + lg * 4 + q];

  const f32x4 zero4 = {0.0f, 0.0f, 0.0f, 0.0f};
  float lpair = 0.0f;
  float rsum[4] = {0.0f, 0.0f, 0.0f, 0.0f};

  // ---- pass 1: diff^2 + row sums (pipelined over 8 tiles) ----
  #pragma unroll 1
  for (int t = 0; t < 8; ++t) {
    const int cur = t & 1;
    bf16x8 v0, v1, u0, u1;
    if (t < 7) {
      const int jn = (t + 1) * TROWS;
      v0 = *(const bf16x8*)(sbf + (hb + jn + s_r0) * DHn + s_c);
      v1 = *(const bf16x8*)(sbf + (hb + jn + s_r1) * DHn + s_c);
      u0 = *(const bf16x8*)(tbf + (hb + jn + s_r0) * DHn + s_c);
      u1 = *(const bf16x8*)(tbf + (hb + jn + s_r1) * DHn + s_c);
    }
    #pragma unroll
    for (int c = 0; c < 4; ++c) {
      const int jl = c * 16;
      const int j0 = t * TROWS + jl;
      const unsigned short* pbs = &Bs[cur][(jl + lr) * BST + lg * 8];
      const unsigned short* pbt = &Bt[cur][(jl + lr) * BST + lg * 8];
      bf16x8 sb0 = *(const bf16x8*)pbs;
      bf16x8 sb1 = *(const bf16x8*)(pbs + 32);
      bf16x8 tb0 = *(const bf16x8*)pbt;
      bf16x8 tb1 = *(const bf16x8*)(pbt + 32);
      f32x4 sacc = __builtin_amdgcn_mfma_f32_16x16x32_bf16(sa0, sb0, zero4, 0, 0, 0);
      sacc = __builtin_amdgcn_mfma_f32_16x16x32_bf16(sa1, sb1, sacc, 0, 0, 0);
      f32x4 tacc = __builtin_amdgcn_mfma_f32_16x16x32_bf16(ta0, tb0, zero4, 0, 0, 0);
      tacc = __builtin_amdgcn_mfma_f32_16x16x32_bf16(ta1, tb1, tacc, 0, 0, 0);
      const float mj = Mcol[j0 + lr];
      #pragma unroll
      for (int q = 0; q < 4; ++q) {
        const float mm = mrow[q] * mj;
        const float ss = sacc[q] * 0.125f * mm;
        const float st = tacc[q] * 0.125f * mm;
        const float d = ss - st;
        lpair += d * d;
        rsum[q] += __expf(st + (1.0f - mm) * (-10000.0f));
      }
    }
    if (t < 7) {
      const int nxt = cur ^ 1;
      *(bf16x8*)&Bs[nxt][s_r0 * BST + s_c] = v0;
      *(bf16x8*)&Bs[nxt][s_r1 * BST + s_c] = v1;
      *(bf16x8*)&Bt[nxt][s_r0 * BST + s_c] = u0;
      *(bf16x8*)&Bt[nxt][s_r1 * BST + s_c] = u1;
    }
    __syncthreads();
  }

  #pragma unroll
  for (int o = 1; o < 16; o <<= 1) {
    #pragma unroll
    for (int q = 0; q < 4; ++q) rsum[q] += __shfl_xor(rsum[q], o, 64);
  }
  float rscale[4];
  #pragma unroll
  for (int q = 0; q < 4; ++q)
    rscale[q] = mrow[q] / fmaxf(rsum[q], 1e-30f);

  // ---- pass 2: recompute e (t only), scale, column sums (pipelined) ----
  {
    bf16x8 u0 = *(const bf16x8*)(tbf + (hb + s_r0) * DHn + s_c);
    bf16x8 u1 = *(const bf16x8*)(tbf + (hb + s_r1) * DHn + s_c);
    *(bf16x8*)&Bt[0][s_r0 * BST + s_c] = u0;
    *(bf16x8*)&Bt[0][s_r1 * BST + s_c] = u1;
  }
  __syncthreads();

  #pragma unroll 1
  for (int t = 0; t < 8; ++t) {
    const int cur = t & 1;
    bf16x8 u0, u1;
    if (t < 7) {
      const int jn = (t + 1) * TROWS;
      u0 = *(const bf16x8*)(tbf + (hb + jn + s_r0) * DHn + s_c);
      u1 = *(const bf16x8*)(tbf + (hb + jn + s_r1) * DHn + s_c);
    }
    #pragma unroll
    for (int c = 0; c < 4; ++c) {
      const int jl = c * 16;
      const int j0 = t * TROWS + jl;
      const unsigned short* pbt = &Bt[cur][(jl + lr) * BST + lg * 8];
      bf16x8 tb0 = *(const bf16x8*)pbt;
      bf16x8 tb1 = *(const bf16x8*)(pbt + 32);
      f32x4 tacc = __builtin_amdgcn_mfma_f32_16x16x32_bf16(ta0, tb0, zero4, 0, 0, 0);
      tacc = __builtin_amdgcn_mfma_f32_16x16x32_bf16(ta1, tb1, tacc, 0, 0, 0);
      const float mj = Mcol[j0 + lr];
      float pc = 0.0f;
      #pragma unroll
      for (int q = 0; q < 4; ++q) {
        const float mm = mrow[q] * mj;
        const float st = tacc[q] * 0.125f * mm;
        const float e = __expf(st + (1.0f - mm) * (-10000.0f));
        pc += e * rscale[q];
      }
      pc += __shfl_xor(pc, 16, 64);
      pc += __shfl_xor(pc, 32, 64);
      if (lg == 0) atomicAdd(&gcol[j0 + lr], pc);
    }
    if (t < 7) {
      const int nxt = cur ^ 1;
      *(bf16x8*)&Bt[nxt][s_r0 * BST + s_c] = u0;
      *(bf16x8*)&Bt[nxt][s_r1 * BST + s_c] = u1;
    }
    __syncthreads();
  }

  #pragma unroll
  for (int o = 1; o < 64; o <<= 1) lpair += __shfl_xor(lpair, o, 64);
  if (lane == 0) wred[w] = lpair;
  __syncthreads();

  if (tid == 0) {
    atomicAdd(&acc[0], (double)((wred[0] + wred[1]) + (wred[2] + wred[3])));
  }
  {
    const int j0 = tid, j1 = tid + 256;
    atomicAdd(&g_score[b * Ln + j0], gcol[j0] * Mcol[j0]);
    atomicAdd(&g_score[b * Ln + j1], gcol[j1] * Mcol[j1]);
  }
}

// ---------------------------------------------------------------------------
// Kernel B (+ inline topk_g): one block per (b, h) = 96 blocks. Writes its
// own loc_part[h] slice NON-atomically (every element stored -> no zeroing).
// ---------------------------------------------------------------------------
__global__ __launch_bounds__(256, 4) void pairB_kernel(
    const unsigned short* __restrict__ tbf, const float* __restrict__ mask,
    const float* __restrict__ g_score, int* __restrict__ g_top,
    float* __restrict__ loc_part) {
  const int b = blockIdx.x & 7;
  const int h = blockIdx.x >> 3;
  const int tid = threadIdx.x;
  const int w = tid >> 6, lane = tid & 63;
  const int lr = lane & 15, lg = lane >> 4;
  const int cw = w * 128;

  __shared__ int gidx[32];
  __shared__ float mrow_s[32];
  __shared__ float rscale_s[32];
  __shared__ float redsum[4][32];
  __shared__ float McolB[Ln];
  __shared__ unsigned short es[32][Ln + 8];

  for (int j = tid; j < Ln; j += 256) McolB[j] = mask[b * Ln + j];
  if (w == 1 && lane < 32 - K1n) gidx[K1n + lane] = 0;
  if (w == 0) {
    float v[8];
    #pragma unroll
    for (int q = 0; q < 8; ++q) v[q] = g_score[b * Ln + q * 64 + lane];
    for (int r = 0; r < K1n; ++r) {
      float bv = v[0]; int bq = 0;
      #pragma unroll
      for (int q = 1; q < 8; ++q) if (v[q] > bv) { bv = v[q]; bq = q; }
      int bj = bq * 64 + lane;
      #pragma unroll
      for (int o = 1; o < 64; o <<= 1) {
        float ov = __shfl_xor(bv, o, 64);
        int oj = __shfl_xor(bj, o, 64);
        if (ov > bv || (ov == bv && oj < bj)) { bv = ov; bj = oj; }
      }
      if (lane == 0) {
        gidx[r] = bj;
        if (h == 0) g_top[b * K1n + r] = bj;
      }
      const int wq = bj >> 6, wl = bj & 63;
      #pragma unroll
      for (int q = 0; q < 8; ++q)
        if (q == wq && lane == wl) v[q] = -3.0e38f;
    }
  }
  __syncthreads();
  if (tid < 32) mrow_s[tid] = (tid < K1n) ? McolB[gidx[tid]] : 0.0f;
  __syncthreads();

  const size_t hb = (size_t)(b * NHn + h) * Ln;
  bf16x8 ta[2][2];
  #pragma unroll
  for (int rt = 0; rt < 2; ++rt) {
    const unsigned short* p = tbf + (hb + gidx[rt * 16 + lr]) * DHn + lg * 8;
    ta[rt][0] = *(const bf16x8*)p;
    ta[rt][1] = *(const bf16x8*)(p + 32);
  }
  const f32x4 zero4 = {0.0f, 0.0f, 0.0f, 0.0f};
  float rsum[2][4] = {{0, 0, 0, 0}, {0, 0, 0, 0}};
  #pragma unroll 1
  for (int ct = 0; ct < 8; ++ct) {
    const int j0 = cw + ct * 16;
    const unsigned short* pb = tbf + (hb + j0 + lr) * DHn + lg * 8;
    bf16x8 tb0 = *(const bf16x8*)pb;
    bf16x8 tb1 = *(const bf16x8*)(pb + 32);
    const float mj = McolB[j0 + lr];
    #pragma unroll
    for (int rt = 0; rt < 2; ++rt) {
      f32x4 tacc = __builtin_amdgcn_mfma_f32_16x16x32_bf16(ta[rt][0], tb0, zero4, 0, 0, 0);
      tacc = __builtin_amdgcn_mfma_f32_16x16x32_bf16(ta[rt][1], tb1, tacc, 0, 0, 0);
      #pragma unroll
      for (int q = 0; q < 4; ++q) {
        const int ri = rt * 16 + lg * 4 + q;
        const float mm = mrow_s[ri] * mj;
        const float st = tacc[q] * 0.125f * mm;
        const float e = __expf(st + (1.0f - mm) * (-10000.0f));
        rsum[rt][q] += e;
        es[ri][j0 + lr] = f2bf(e);
      }
    }
  }
  #pragma unroll
  for (int o = 1; o < 16; o <<= 1) {
    #pragma unroll
    for (int rt = 0; rt < 2; ++rt)
      #pragma unroll
      for (int q = 0; q < 4; ++q) rsum[rt][q] += __shfl_xor(rsum[rt][q], o, 64);
  }
  if (lr == 0) {
    #pragma unroll
    for (int rt = 0; rt < 2; ++rt)
      #pragma unroll
      for (int q = 0; q < 4; ++q) redsum[w][rt * 16 + lg * 4 + q] = rsum[rt][q];
  }
  __syncthreads();
  if (tid < 32) {
    const float fs = redsum[0][tid] + redsum[1][tid] + redsum[2][tid] + redsum[3][tid];
    rscale_s[tid] = mrow_s[tid] / fmaxf(fs, 1e-30f);
  }
  __syncthreads();
  float* lp = loc_part + (size_t)(h * Bn + b) * K1n * Ln;
  for (int idx = tid; idx < K1n * Ln; idx += 256) {
    const int ri = idx >> 9, j = idx & (Ln - 1);
    const float e = bf2f(es[ri][j]);
    lp[idx] = e * rscale_s[ri] * McolB[j];     // non-atomic, full coverage
  }
}

// ---------------------------------------------------------------------------
// Triplet (+ inline topk_l summing 12 head-partials, + last-block finalize).
// ---------------------------------------------------------------------------
#define TP (Dn + 16)

__global__ __launch_bounds__(256, 1) void triplet_kernel(
    const float* __restrict__ s_rep, const float* __restrict__ t_rep,
    const float* __restrict__ mask, const int* __restrict__ g_top,
    const float* __restrict__ loc_part, double* __restrict__ acc,
    unsigned int* __restrict__ done_cnt, float* __restrict__ out) {
  const int blk = blockIdx.x, tid = threadIdx.x;
  const int b = blk / K1n, i1 = blk % K1n;
  const int w = tid >> 6, lane = tid & 63;
  const int lr = lane & 15, lg = lane >> 4;

  __shared__ unsigned short NS[32][TP];
  __shared__ unsigned short NT[32][TP];
  __shared__ int lidx[K2n];
  __shared__ float fl2[K2n];
  __shared__ float sred[4], cred[4];
  __shared__ int is_last;
  __shared__ float red[4];

  const int g = g_top[b * K1n + i1];
  if (w == 0) {
    // top-k over sum of 12 head partials, diagonal zeroed
    const float* r0 = loc_part + (size_t)(b * K1n + i1) * Ln;
    float v[8];
    #pragma unroll
    for (int q = 0; q < 8; ++q) {
      const int j = q * 64 + lane;
      float sv = 0.0f;
      #pragma unroll
      for (int hh = 0; hh < NHn; ++hh)
        sv += r0[(size_t)hh * Bn * K1n * Ln + j];
      v[q] = (j == g) ? 0.0f : sv;
    }
    for (int r = 0; r < K2n; ++r) {
      float bv = v[0]; int bq = 0;
      #pragma unroll
      for (int q = 1; q < 8; ++q) if (v[q] > bv) { bv = v[q]; bq = q; }
      int bj = bq * 64 + lane;
      #pragma unroll
      for (int o = 1; o < 64; o <<= 1) {
        float ov = __shfl_xor(bv, o, 64);
        int oj = __shfl_xor(bj, o, 64);
        if (ov > bv || (ov == bv && oj < bj)) { bv = ov; bj = oj; }
      }
      if (lane == 0) lidx[r] = bj;
      const int wq = bj >> 6, wl = bj & 63;
      #pragma unroll
      for (int q = 0; q < 8; ++q)
        if (q == wq && lane == wl) v[q] = -3.0e38f;
    }
  }
  __syncthreads();
  if (tid < K2n)
    fl2[tid] = (mask[b * Ln + g] + mask[b * Ln + lidx[tid]] == 2.0f) ? 1.0f : 0.0f;
  __syncthreads();

  const float* pgs = s_rep + (size_t)(b * Ln + g) * Dn;
  const float* pgt = t_rep + (size_t)(b * Ln + g) * Dn;
  for (int j = w; j < K2n; j += 4) {
    const float* pls = s_rep + (size_t)(b * Ln + lidx[j]) * Dn;
    const float* plt = t_rep + (size_t)(b * Ln + lidx[j]) * Dn;
    float4 ds[3], dt[3];
    float ssq = 0.0f, tsq = 0.0f;
    #pragma unroll
    for (int q = 0; q < 3; ++q) {
      const int c = lane * 4 + q * 256;
      float4 a = *(const float4*)&pgs[c];
      float4 x = *(const float4*)&pls[c];
      ds[q] = make_float4(a.x - x.x, a.y - x.y, a.z - x.z, a.w - x.w);
      ssq += ds[q].x * ds[q].x + ds[q].y * ds[q].y + ds[q].z * ds[q].z + ds[q].w * ds[q].w;
      float4 c2 = *(const float4*)&pgt[c];
      float4 y = *(const float4*)&plt[c];
      dt[q] = make_float4(c2.x - y.x, c2.y - y.y, c2.z - y.z, c2.w - y.w);
      tsq += dt[q].x * dt[q].x + dt[q].y * dt[q].y + dt[q].z * dt[q].z + dt[q].w * dt[q].w;
    }
    #pragma unroll
    for (int o = 1; o < 64; o <<= 1) {
      ssq += __shfl_xor(ssq, o, 64);
      tsq += __shfl_xor(tsq, o, 64);
    }
    const float sinv = 1.0f / fmaxf(sqrtf(ssq), 1e-12f);
    const float tinv = 1.0f / fmaxf(sqrtf(tsq), 1e-12f);
    #pragma unroll
    for (int q = 0; q < 3; ++q) {
      const int c = lane * 4 + q * 256;
      ushort4 us, ut;
      us.x = f2bf(ds[q].x * sinv); us.y = f2bf(ds[q].y * sinv);
      us.z = f2bf(ds[q].z * sinv); us.w = f2bf(ds[q].w * sinv);
      ut.x = f2bf(dt[q].x * tinv); ut.y = f2bf(dt[q].y * tinv);
      ut.z = f2bf(dt[q].z * tinv); ut.w = f2bf(dt[q].w * tinv);
      *(ushort4*)&NS[j][c] = us;
      *(ushort4*)&NT[j][c] = ut;
    }
  }
  __syncthreads();

  const int qr = w >> 1, qc = w & 1;
  f32x4 sacc = {0.0f, 0.0f, 0.0f, 0.0f};
  f32x4 tacc = {0.0f, 0.0f, 0.0f, 0.0f};
  #pragma unroll
  for (int ks = 0; ks < 24; ++ks) {
    const int kk = ks * 32 + lg * 8;
    bf16x8 as = *(const bf16x8*)&NS[qr * 16 + lr][kk];
    bf16x8 bs = *(const bf16x8*)&NS[qc * 16 + lr][kk];
    bf16x8 at = *(const bf16x8*)&NT[qr * 16 + lr][kk];
    bf16x8 bt = *(const bf16x8*)&NT[qc * 16 + lr][kk];
    sacc = __builtin_amdgcn_mfma_f32_16x16x32_bf16(as, bs, sacc, 0, 0, 0);
    tacc = __builtin_amdgcn_mfma_f32_16x16x32_bf16(at, bt, tacc, 0, 0, 0);
  }
  float psum = 0.0f, pcnt = 0.0f;
  #pragma unroll
  for (int q = 0; q < 4; ++q) {
    const int j2 = qr * 16 + lg * 4 + q;
    const int k2 = qc * 16 + lr;
    if (j2 < K2n && k2 < K2n && j2 != k2) {
      const float am = fl2[j2] * fl2[k2];
      const bool smv = (am != 0.0f) && (sacc[q] != 0.0f);
      const bool tmv = (am != 0.0f) && (tacc[q] != 0.0f);
      const float sv = smv ? sacc[q] : 0.0f;
      const float tv = tmv ? tacc[q] : 0.0f;
      const float d = sv - tv;
      const float ad = fabsf(d);
      psum += (ad < 1.0f) ? 0.5f * d * d : (ad - 0.5f);
      pcnt += smv ? 1.0f : 0.0f;
    }
  }
  #pragma unroll
  for (int o = 1; o < 64; o <<= 1) {
    psum += __shfl_xor(psum, o, 64);
    pcnt += __shfl_xor(pcnt, o, 64);
  }
  if (lane == 0) { sred[w] = psum; cred[w] = pcnt; }
  __syncthreads();
  if (tid == 0) {
    atomicAdd(&acc[1], (double)(sred[0] + sred[1] + sred[2] + sred[3]));
    atomicAdd(&acc[2], (double)(cred[0] + cred[1] + cred[2] + cred[3]));
    __threadfence();
    const unsigned int done = atomicAdd(done_cnt, 1u);
    is_last = (done == (unsigned int)(Bn * K1n - 1)) ? 1 : 0;
  }
  __syncthreads();

  if (is_last) {
    double sm = 0.0;
    for (int bb = 0; bb < Bn; ++bb) {
      float p = 0.0f;
      for (int i = tid; i < Ln; i += 256) p += mask[bb * Ln + i];
      #pragma unroll
      for (int o = 1; o < 64; o <<= 1) p += __shfl_xor(p, o, 64);
      __syncthreads();
      if ((tid & 63) == 0) red[tid >> 6] = p;
      __syncthreads();
      if (tid == 0) {
        float rs = red[0] + red[1] + red[2] + red[3];
        sm += (double)rs * (double)rs;
      }
    }
    __syncthreads();
    if (tid == 0) {
      const double a0 = atomicAdd(&acc[0], 0.0);
      const double a1 = atomicAdd(&acc[1], 0.0);
      const double a2 = atomicAdd(&acc[2], 0.0);
      const double lp = a0 / ((double)NHn * sm);
      const double lt = a1 / a2;
      out[0] = (float)(lp + lt);
    }
  }
}

// ---------------------------------------------------------------------------
extern "C" void kernel_launch(void* const* d_in, const int* in_sizes, int n_in,
                              void* d_out, int out_size, void* d_ws, size_t ws_size,
                              hipStream_t stream) {
  const float* s_rep = (const float*)d_in[0];
  const float* t_rep = (const float*)d_in[1];
  const float* mask  = (const float*)d_in[2];
  float* out = (float*)d_out;

  char* w = (char*)d_ws;
  double* acc      = (double*)(w + WS_ACC);
  unsigned int* done_cnt = (unsigned int*)(w + WS_ACC + 48);
  float* g_score   = (float*)(w + WS_GSCORE);
  int* g_top       = (int*)(w + WS_GTOP);
  float* loc_part  = (float*)(w + WS_LOCP);
  unsigned short* sbf = (unsigned short*)(w + WS_SBF);
  unsigned short* tbf = (unsigned short*)(w + WS_TBF);

  prep_bf16_kernel<<<Bn * Ln * Dn / 4 / 256, 256, 0, stream>>>(
      s_rep, t_rep, sbf, tbf, g_score, (int*)(w + WS_ACC));
  pairA_kernel<<<Bn * NHn * (Ln / 64), 256, 0, stream>>>(sbf, tbf, mask, g_score, acc);
  pairB_kernel<<<Bn * NHn, 256, 0, stream>>>(tbf, mask, g_score, g_top, loc_part);
  triplet_kernel<<<Bn * K1n, 256, 0, stream>>>(s_rep, t_rep, mask, g_top, loc_part,
                                               acc, done_cnt, out);
}

// Round 13
// 100.157 us; speedup vs baseline: 1.7283x; 1.0304x over previous
//
#include <hip/hip_runtime.h>
#include <hip/hip_bf16.h>
#include <math.h>

#define Bn 8
#define Ln 512
#define Dn 768
#define NHn 12
#define DHn 64
#define K1n 20
#define K2n 20
#define BST 72    // LDS B-tile row stride in shorts
#define TROWS 64  // B-tile rows per stage

// workspace layout (bytes) -- NO memset: acc/g_score zeroed by prep block 0,
// loc_part is fully written non-atomically by pairB (no init needed).
#define WS_ACC    0          // double acc[8]; bytes 48..51 = done-counter
#define WS_GSCORE 64         // float g_score[8*512] (16 KB)
#define WS_GTOP   16448      // int g_top[8*20]
#define WS_LOCP   17152      // float loc_part[12][8][20][512] (3.93 MB)
#define WS_SBF    3949312    // ushort sbf[8*12*512*64] bf16 head-major
#define WS_TBF    10240768   // ushort tbf[...] (ends 16532224)

typedef __attribute__((ext_vector_type(8))) short bf16x8;
typedef __attribute__((ext_vector_type(4))) float f32x4;

__device__ inline unsigned short f2bf(float x) {
  __hip_bfloat16 h = __float2bfloat16(x);
  return *reinterpret_cast<unsigned short*>(&h);
}
__device__ inline float bf2f(unsigned short u) {
  return __uint_as_float(((unsigned int)u) << 16);
}

// ---------------------------------------------------------------------------
// Prep: fp32 [b][row][h*64+k] -> bf16 head-major [b][h][row][k].
// Block 0 zeroes acc + g_score (the 268 MB fill in the PMC is the harness's
// one-time d_ws poison, not in the replay path).
// ---------------------------------------------------------------------------
__global__ __launch_bounds__(256) void prep_bf16_kernel(
    const float* __restrict__ s, const float* __restrict__ t,
    unsigned short* __restrict__ sbf, unsigned short* __restrict__ tbf,
    float* __restrict__ g_score, int* __restrict__ accw) {
  int tid = threadIdx.x;
  if (blockIdx.x == 0) {
    if (tid < 16) accw[tid] = 0;                       // acc[0..7] + done
    for (int i = tid; i < Bn * Ln; i += 256) g_score[i] = 0.0f;
  }
  int gid = blockIdx.x * 256 + tid;
  int f = gid * 4;
  int col = f % Dn;
  int rb = f / Dn;
  int row = rb & (Ln - 1);
  int b = rb >> 9;
  int h = col >> 6;
  int k = col & 63;
  size_t dst = (((size_t)(b * NHn + h) * Ln + row) * DHn + k);
  float4 vs = *(const float4*)(s + f);
  float4 vt = *(const float4*)(t + f);
  ushort4 us, ut;
  us.x = f2bf(vs.x); us.y = f2bf(vs.y); us.z = f2bf(vs.z); us.w = f2bf(vs.w);
  ut.x = f2bf(vt.x); ut.y = f2bf(vt.y); ut.z = f2bf(vt.z); ut.w = f2bf(vt.w);
  *(ushort4*)(sbf + dst) = us;
  *(ushort4*)(tbf + dst) = ut;
}

// ---------------------------------------------------------------------------
// Kernel A v4 (unchanged from round 11): software-pipelined LDS staging.
// ---------------------------------------------------------------------------
__global__ __launch_bounds__(256) void pairA_kernel(
    const unsigned short* __restrict__ sbf, const unsigned short* __restrict__ tbf,
    const float* __restrict__ mask, float* __restrict__ g_score,
    double* __restrict__ acc) {
  const int b = blockIdx.x & 7;
  const int r = blockIdx.x >> 3;          // 0..95
  const int it = r / NHn;                 // 0..7
  const int h = r - it * NHn;             // 0..11
  const int tid = threadIdx.x;
  const int w = tid >> 6;                 // wave: rows [it*64 + w*16, +16)
  const int lane = tid & 63;
  const int lr = lane & 15, lg = lane >> 4;

  __shared__ unsigned short Bs[2][TROWS * BST];
  __shared__ unsigned short Bt[2][TROWS * BST];
  __shared__ float Mcol[Ln];
  __shared__ float gcol[Ln];
  __shared__ float wred[4];

  const int s_r0 = tid >> 3;              // 0..31
  const int s_r1 = s_r0 + 32;             // 32..63
  const int s_c = (tid & 7) * 8;

  for (int j = tid; j < Ln; j += 256) {
    Mcol[j] = mask[b * Ln + j];
    gcol[j] = 0.0f;
  }

  const size_t hb = (size_t)(b * NHn + h) * Ln;
  const int rw = it * 64 + w * 16;
  const unsigned short* pas = sbf + (hb + rw + lr) * DHn + lg * 8;
  const unsigned short* pat = tbf + (hb + rw + lr) * DHn + lg * 8;
  bf16x8 sa0 = *(const bf16x8*)pas;
  bf16x8 sa1 = *(const bf16x8*)(pas + 32);
  bf16x8 ta0 = *(const bf16x8*)pat;
  bf16x8 ta1 = *(const bf16x8*)(pat + 32);

  {
    bf16x8 v0 = *(const bf16x8*)(sbf + (hb + s_r0) * DHn + s_c);
    bf16x8 v1 = *(const bf16x8*)(sbf + (hb + s_r1) * DHn + s_c);
    bf16x8 u0 = *(const bf16x8*)(tbf + (hb + s_r0) * DHn + s_c);
    bf16x8 u1 = *(const bf16x8*)(tbf + (hb + s_r1) * DHn + s_c);
    *(bf16x8*)&Bs[0][s_r0 * BST + s_c] = v0;
    *(bf16x8*)&Bs[0][s_r1 * BST + s_c] = v1;
    *(bf16x8*)&Bt[0][s_r0 * BST + s_c] = u0;
    *(bf16x8*)&Bt[0][s_r1 * BST + s_c] = u1;
  }
  __syncthreads();

  float mrow[4];
  #pragma unroll
  for (int q = 0; q < 4; ++q) mrow[q] = Mcol[rw + lg * 4 + q];

  const f32x4 zero4 = {0.0f, 0.0f, 0.0f, 0.0f};
  float lpair = 0.0f;
  float rsum[4] = {0.0f, 0.0f, 0.0f, 0.0f};

  // ---- pass 1: diff^2 + row sums (pipelined over 8 tiles) ----
  #pragma unroll 1
  for (int t = 0; t < 8; ++t) {
    const int cur = t & 1;
    bf16x8 v0, v1, u0, u1;
    if (t < 7) {
      const int jn = (t + 1) * TROWS;
      v0 = *(const bf16x8*)(sbf + (hb + jn + s_r0) * DHn + s_c);
      v1 = *(const bf16x8*)(sbf + (hb + jn + s_r1) * DHn + s_c);
      u0 = *(const bf16x8*)(tbf + (hb + jn + s_r0) * DHn + s_c);
      u1 = *(const bf16x8*)(tbf + (hb + jn + s_r1) * DHn + s_c);
    }
    #pragma unroll
    for (int c = 0; c < 4; ++c) {
      const int jl = c * 16;
      const int j0 = t * TROWS + jl;
      const unsigned short* pbs = &Bs[cur][(jl + lr) * BST + lg * 8];
      const unsigned short* pbt = &Bt[cur][(jl + lr) * BST + lg * 8];
      bf16x8 sb0 = *(const bf16x8*)pbs;
      bf16x8 sb1 = *(const bf16x8*)(pbs + 32);
      bf16x8 tb0 = *(const bf16x8*)pbt;
      bf16x8 tb1 = *(const bf16x8*)(pbt + 32);
      f32x4 sacc = __builtin_amdgcn_mfma_f32_16x16x32_bf16(sa0, sb0, zero4, 0, 0, 0);
      sacc = __builtin_amdgcn_mfma_f32_16x16x32_bf16(sa1, sb1, sacc, 0, 0, 0);
      f32x4 tacc = __builtin_amdgcn_mfma_f32_16x16x32_bf16(ta0, tb0, zero4, 0, 0, 0);
      tacc = __builtin_amdgcn_mfma_f32_16x16x32_bf16(ta1, tb1, tacc, 0, 0, 0);
      const float mj = Mcol[j0 + lr];
      #pragma unroll
      for (int q = 0; q < 4; ++q) {
        const float mm = mrow[q] * mj;
        const float ss = sacc[q] * 0.125f * mm;
        const float st = tacc[q] * 0.125f * mm;
        const float d = ss - st;
        lpair += d * d;
        rsum[q] += __expf(st + (1.0f - mm) * (-10000.0f));
      }
    }
    if (t < 7) {
      const int nxt = cur ^ 1;
      *(bf16x8*)&Bs[nxt][s_r0 * BST + s_c] = v0;
      *(bf16x8*)&Bs[nxt][s_r1 * BST + s_c] = v1;
      *(bf16x8*)&Bt[nxt][s_r0 * BST + s_c] = u0;
      *(bf16x8*)&Bt[nxt][s_r1 * BST + s_c] = u1;
    }
    __syncthreads();
  }

  #pragma unroll
  for (int o = 1; o < 16; o <<= 1) {
    #pragma unroll
    for (int q = 0; q < 4; ++q) rsum[q] += __shfl_xor(rsum[q], o, 64);
  }
  float rscale[4];
  #pragma unroll
  for (int q = 0; q < 4; ++q)
    rscale[q] = mrow[q] / fmaxf(rsum[q], 1e-30f);

  // ---- pass 2: recompute e (t only), scale, column sums (pipelined) ----
  {
    bf16x8 u0 = *(const bf16x8*)(tbf + (hb + s_r0) * DHn + s_c);
    bf16x8 u1 = *(const bf16x8*)(tbf + (hb + s_r1) * DHn + s_c);
    *(bf16x8*)&Bt[0][s_r0 * BST + s_c] = u0;
    *(bf16x8*)&Bt[0][s_r1 * BST + s_c] = u1;
  }
  __syncthreads();

  #pragma unroll 1
  for (int t = 0; t < 8; ++t) {
    const int cur = t & 1;
    bf16x8 u0, u1;
    if (t < 7) {
      const int jn = (t + 1) * TROWS;
      u0 = *(const bf16x8*)(tbf + (hb + jn + s_r0) * DHn + s_c);
      u1 = *(const bf16x8*)(tbf + (hb + jn + s_r1) * DHn + s_c);
    }
    #pragma unroll
    for (int c = 0; c < 4; ++c) {
      const int jl = c * 16;
      const int j0 = t * TROWS + jl;
      const unsigned short* pbt = &Bt[cur][(jl + lr) * BST + lg * 8];
      bf16x8 tb0 = *(const bf16x8*)pbt;
      bf16x8 tb1 = *(const bf16x8*)(pbt + 32);
      f32x4 tacc = __builtin_amdgcn_mfma_f32_16x16x32_bf16(ta0, tb0, zero4, 0, 0, 0);
      tacc = __builtin_amdgcn_mfma_f32_16x16x32_bf16(ta1, tb1, tacc, 0, 0, 0);
      const float mj = Mcol[j0 + lr];
      float pc = 0.0f;
      #pragma unroll
      for (int q = 0; q < 4; ++q) {
        const float mm = mrow[q] * mj;
        const float st = tacc[q] * 0.125f * mm;
        const float e = __expf(st + (1.0f - mm) * (-10000.0f));
        pc += e * rscale[q];
      }
      pc += __shfl_xor(pc, 16, 64);
      pc += __shfl_xor(pc, 32, 64);
      if (lg == 0) atomicAdd(&gcol[j0 + lr], pc);
    }
    if (t < 7) {
      const int nxt = cur ^ 1;
      *(bf16x8*)&Bt[nxt][s_r0 * BST + s_c] = u0;
      *(bf16x8*)&Bt[nxt][s_r1 * BST + s_c] = u1;
    }
    __syncthreads();
  }

  #pragma unroll
  for (int o = 1; o < 64; o <<= 1) lpair += __shfl_xor(lpair, o, 64);
  if (lane == 0) wred[w] = lpair;
  __syncthreads();

  if (tid == 0) {
    atomicAdd(&acc[0], (double)((wred[0] + wred[1]) + (wred[2] + wred[3])));
  }
  {
    const int j0 = tid, j1 = tid + 256;
    atomicAdd(&g_score[b * Ln + j0], gcol[j0] * Mcol[j0]);
    atomicAdd(&g_score[b * Ln + j1], gcol[j1] * Mcol[j1]);
  }
}

// ---------------------------------------------------------------------------
// Kernel B (+ inline topk_g): one block per (b, h) = 96 blocks. Writes its
// own loc_part[h] slice NON-atomically.
// ---------------------------------------------------------------------------
__global__ __launch_bounds__(256, 4) void pairB_kernel(
    const unsigned short* __restrict__ tbf, const float* __restrict__ mask,
    const float* __restrict__ g_score, int* __restrict__ g_top,
    float* __restrict__ loc_part) {
  const int b = blockIdx.x & 7;
  const int h = blockIdx.x >> 3;
  const int tid = threadIdx.x;
  const int w = tid >> 6, lane = tid & 63;
  const int lr = lane & 15, lg = lane >> 4;
  const int cw = w * 128;

  __shared__ int gidx[32];
  __shared__ float mrow_s[32];
  __shared__ float rscale_s[32];
  __shared__ float redsum[4][32];
  __shared__ float McolB[Ln];
  __shared__ unsigned short es[32][Ln + 8];

  for (int j = tid; j < Ln; j += 256) McolB[j] = mask[b * Ln + j];
  if (w == 1 && lane < 32 - K1n) gidx[K1n + lane] = 0;
  if (w == 0) {
    float v[8];
    #pragma unroll
    for (int q = 0; q < 8; ++q) v[q] = g_score[b * Ln + q * 64 + lane];
    for (int r = 0; r < K1n; ++r) {
      float bv = v[0]; int bq = 0;
      #pragma unroll
      for (int q = 1; q < 8; ++q) if (v[q] > bv) { bv = v[q]; bq = q; }
      int bj = bq * 64 + lane;
      #pragma unroll
      for (int o = 1; o < 64; o <<= 1) {
        float ov = __shfl_xor(bv, o, 64);
        int oj = __shfl_xor(bj, o, 64);
        if (ov > bv || (ov == bv && oj < bj)) { bv = ov; bj = oj; }
      }
      if (lane == 0) {
        gidx[r] = bj;
        if (h == 0) g_top[b * K1n + r] = bj;
      }
      const int wq = bj >> 6, wl = bj & 63;
      #pragma unroll
      for (int q = 0; q < 8; ++q)
        if (q == wq && lane == wl) v[q] = -3.0e38f;
    }
  }
  __syncthreads();
  if (tid < 32) mrow_s[tid] = (tid < K1n) ? McolB[gidx[tid]] : 0.0f;
  __syncthreads();

  const size_t hb = (size_t)(b * NHn + h) * Ln;
  bf16x8 ta[2][2];
  #pragma unroll
  for (int rt = 0; rt < 2; ++rt) {
    const unsigned short* p = tbf + (hb + gidx[rt * 16 + lr]) * DHn + lg * 8;
    ta[rt][0] = *(const bf16x8*)p;
    ta[rt][1] = *(const bf16x8*)(p + 32);
  }
  const f32x4 zero4 = {0.0f, 0.0f, 0.0f, 0.0f};
  float rsum[2][4] = {{0, 0, 0, 0}, {0, 0, 0, 0}};
  #pragma unroll 1
  for (int ct = 0; ct < 8; ++ct) {
    const int j0 = cw + ct * 16;
    const unsigned short* pb = tbf + (hb + j0 + lr) * DHn + lg * 8;
    bf16x8 tb0 = *(const bf16x8*)pb;
    bf16x8 tb1 = *(const bf16x8*)(pb + 32);
    const float mj = McolB[j0 + lr];
    #pragma unroll
    for (int rt = 0; rt < 2; ++rt) {
      f32x4 tacc = __builtin_amdgcn_mfma_f32_16x16x32_bf16(ta[rt][0], tb0, zero4, 0, 0, 0);
      tacc = __builtin_amdgcn_mfma_f32_16x16x32_bf16(ta[rt][1], tb1, tacc, 0, 0, 0);
      #pragma unroll
      for (int q = 0; q < 4; ++q) {
        const int ri = rt * 16 + lg * 4 + q;
        const float mm = mrow_s[ri] * mj;
        const float st = tacc[q] * 0.125f * mm;
        const float e = __expf(st + (1.0f - mm) * (-10000.0f));
        rsum[rt][q] += e;
        es[ri][j0 + lr] = f2bf(e);
      }
    }
  }
  #pragma unroll
  for (int o = 1; o < 16; o <<= 1) {
    #pragma unroll
    for (int rt = 0; rt < 2; ++rt)
      #pragma unroll
      for (int q = 0; q < 4; ++q) rsum[rt][q] += __shfl_xor(rsum[rt][q], o, 64);
  }
  if (lr == 0) {
    #pragma unroll
    for (int rt = 0; rt < 2; ++rt)
      #pragma unroll
      for (int q = 0; q < 4; ++q) redsum[w][rt * 16 + lg * 4 + q] = rsum[rt][q];
  }
  __syncthreads();
  if (tid < 32) {
    const float fs = redsum[0][tid] + redsum[1][tid] + redsum[2][tid] + redsum[3][tid];
    rscale_s[tid] = mrow_s[tid] / fmaxf(fs, 1e-30f);
  }
  __syncthreads();
  float* lp = loc_part + (size_t)(h * Bn + b) * K1n * Ln;
  for (int idx = tid; idx < K1n * Ln; idx += 256) {
    const int ri = idx >> 9, j = idx & (Ln - 1);
    const float e = bf2f(es[ri][j]);
    lp[idx] = e * rscale_s[ri] * McolB[j];     // non-atomic, full coverage
  }
}

// ---------------------------------------------------------------------------
// Triplet v2: 512 threads (8 waves), phase-parallel. Round 12 PMC: 44-48 us
// at 5% occupancy / 2.6% VALUBusy -- every phase was a serial chain on 4
// waves. Now: locsum (12-partial sum) by 512 threads in parallel; g-row
// staged to LDS once (reused 20x); diff rows over 8 waves; Gram as 8
// wave-tasks ({s,t} x 4 quadrants) exchanged via LDS. Garbage in NS/NT rows
// 20..31 cannot contaminate G[j<20][k<20] (MFMA rows/cols are independent).
// ---------------------------------------------------------------------------
#define TPW (Dn + 16)

__global__ __launch_bounds__(512, 1) void triplet_kernel(
    const float* __restrict__ s_rep, const float* __restrict__ t_rep,
    const float* __restrict__ mask, const int* __restrict__ g_top,
    const float* __restrict__ loc_part, double* __restrict__ acc,
    unsigned int* __restrict__ done_cnt, float* __restrict__ out) {
  const int blk = blockIdx.x, tid = threadIdx.x;
  const int b = blk / K1n, i1 = blk % K1n;
  const int w = tid >> 6, lane = tid & 63;
  const int lr = lane & 15, lg = lane >> 4;

  __shared__ unsigned short NS[32][TPW];
  __shared__ unsigned short NT[32][TPW];
  __shared__ float locsum[Ln];
  __shared__ float gsr[Dn], gtr[Dn];
  __shared__ float G[2][K2n][K2n + 1];
  __shared__ int lidx[K2n];
  __shared__ float fl2[K2n];
  __shared__ float sred[8], cred[8];
  __shared__ int is_last;
  __shared__ float red[8];

  const int g = g_top[b * K1n + i1];

  // phase 0: parallel 12-partial column sums + g-row staging
  {
    const int j = tid;
    float sv = 0.0f;
    #pragma unroll
    for (int hh = 0; hh < NHn; ++hh)
      sv += loc_part[((size_t)(hh * Bn + b) * K1n + i1) * Ln + j];
    locsum[j] = (j == g) ? 0.0f : sv;
  }
  {
    const float* pgs = s_rep + (size_t)(b * Ln + g) * Dn;
    const float* pgt = t_rep + (size_t)(b * Ln + g) * Dn;
    if (tid < 192) {
      *(float4*)&gsr[tid * 4] = *(const float4*)&pgs[tid * 4];
    } else if (tid < 384) {
      const int q4 = tid - 192;
      *(float4*)&gtr[q4 * 4] = *(const float4*)&pgt[q4 * 4];
    }
  }
  __syncthreads();

  // phase 1: wave-0 register top-k over LDS locsum (tie -> lowest index)
  if (w == 0) {
    float v[8];
    #pragma unroll
    for (int q = 0; q < 8; ++q) v[q] = locsum[q * 64 + lane];
    for (int r = 0; r < K2n; ++r) {
      float bv = v[0]; int bq = 0;
      #pragma unroll
      for (int q = 1; q < 8; ++q) if (v[q] > bv) { bv = v[q]; bq = q; }
      int bj = bq * 64 + lane;
      #pragma unroll
      for (int o = 1; o < 64; o <<= 1) {
        float ov = __shfl_xor(bv, o, 64);
        int oj = __shfl_xor(bj, o, 64);
        if (ov > bv || (ov == bv && oj < bj)) { bv = ov; bj = oj; }
      }
      if (lane == 0) lidx[r] = bj;
      const int wq = bj >> 6, wl = bj & 63;
      #pragma unroll
      for (int q = 0; q < 8; ++q)
        if (q == wq && lane == wl) v[q] = -3.0e38f;
    }
  }
  __syncthreads();
  if (tid < K2n)
    fl2[tid] = (mask[b * Ln + g] + mask[b * Ln + lidx[tid]] == 2.0f) ? 1.0f : 0.0f;

  // phase 2: normalized diffs, 20 rows over 8 waves, g-row from LDS
  for (int j = w; j < K2n; j += 8) {
    const float* pls = s_rep + (size_t)(b * Ln + lidx[j]) * Dn;
    const float* plt = t_rep + (size_t)(b * Ln + lidx[j]) * Dn;
    float4 ds[3], dt[3];
    float ssq = 0.0f, tsq = 0.0f;
    #pragma unroll
    for (int q = 0; q < 3; ++q) {
      const int c = lane * 4 + q * 256;
      float4 a = *(const float4*)&gsr[c];
      float4 x = *(const float4*)&pls[c];
      ds[q] = make_float4(a.x - x.x, a.y - x.y, a.z - x.z, a.w - x.w);
      ssq += ds[q].x * ds[q].x + ds[q].y * ds[q].y + ds[q].z * ds[q].z + ds[q].w * ds[q].w;
      float4 c2 = *(const float4*)&gtr[c];
      float4 y = *(const float4*)&plt[c];
      dt[q] = make_float4(c2.x - y.x, c2.y - y.y, c2.z - y.z, c2.w - y.w);
      tsq += dt[q].x * dt[q].x + dt[q].y * dt[q].y + dt[q].z * dt[q].z + dt[q].w * dt[q].w;
    }
    #pragma unroll
    for (int o = 1; o < 64; o <<= 1) {
      ssq += __shfl_xor(ssq, o, 64);
      tsq += __shfl_xor(tsq, o, 64);
    }
    const float sinv = 1.0f / fmaxf(sqrtf(ssq), 1e-12f);
    const float tinv = 1.0f / fmaxf(sqrtf(tsq), 1e-12f);
    #pragma unroll
    for (int q = 0; q < 3; ++q) {
      const int c = lane * 4 + q * 256;
      ushort4 us, ut;
      us.x = f2bf(ds[q].x * sinv); us.y = f2bf(ds[q].y * sinv);
      us.z = f2bf(ds[q].z * sinv); us.w = f2bf(ds[q].w * sinv);
      ut.x = f2bf(dt[q].x * tinv); ut.y = f2bf(dt[q].y * tinv);
      ut.z = f2bf(dt[q].z * tinv); ut.w = f2bf(dt[q].w * tinv);
      *(ushort4*)&NS[j][c] = us;
      *(ushort4*)&NT[j][c] = ut;
    }
  }
  __syncthreads();

  // phase 3: Gram as 8 wave-tasks: tensor = w&1, quadrant = w>>1
  {
    const int ts = w & 1;
    const int qr = w >> 2;
    const int qc = (w >> 1) & 1;
    const unsigned short (*N)[TPW] = ts ? NT : NS;
    f32x4 acc4 = {0.0f, 0.0f, 0.0f, 0.0f};
    #pragma unroll
    for (int ks = 0; ks < 24; ++ks) {
      const int kk = ks * 32 + lg * 8;
      bf16x8 a8 = *(const bf16x8*)&N[qr * 16 + lr][kk];
      bf16x8 b8 = *(const bf16x8*)&N[qc * 16 + lr][kk];
      acc4 = __builtin_amdgcn_mfma_f32_16x16x32_bf16(a8, b8, acc4, 0, 0, 0);
    }
    #pragma unroll
    for (int q = 0; q < 4; ++q) {
      const int j2 = qr * 16 + lg * 4 + q;
      const int k2 = qc * 16 + lr;
      if (j2 < K2n && k2 < K2n) G[ts][j2][k2] = acc4[q];
    }
  }
  __syncthreads();

  // phase 4: huber + masks on 400 pairs
  float psum = 0.0f, pcnt = 0.0f;
  if (tid < K2n * K2n) {
    const int j2 = tid / K2n, k2 = tid - j2 * K2n;
    if (j2 != k2) {
      const float am = fl2[j2] * fl2[k2];
      const float sv0 = G[0][j2][k2];
      const float tv0 = G[1][j2][k2];
      const bool smv = (am != 0.0f) && (sv0 != 0.0f);
      const bool tmv = (am != 0.0f) && (tv0 != 0.0f);
      const float sv = smv ? sv0 : 0.0f;
      const float tv = tmv ? tv0 : 0.0f;
      const float d = sv - tv;
      const float ad = fabsf(d);
      psum = (ad < 1.0f) ? 0.5f * d * d : (ad - 0.5f);
      pcnt = smv ? 1.0f : 0.0f;
    }
  }
  #pragma unroll
  for (int o = 1; o < 64; o <<= 1) {
    psum += __shfl_xor(psum, o, 64);
    pcnt += __shfl_xor(pcnt, o, 64);
  }
  if (lane == 0) { sred[w] = psum; cred[w] = pcnt; }
  __syncthreads();
  if (tid == 0) {
    float ps = 0.0f, pcs = 0.0f;
    #pragma unroll
    for (int i = 0; i < 8; ++i) { ps += sred[i]; pcs += cred[i]; }
    atomicAdd(&acc[1], (double)ps);
    atomicAdd(&acc[2], (double)pcs);
    __threadfence();
    const unsigned int done = atomicAdd(done_cnt, 1u);
    is_last = (done == (unsigned int)(Bn * K1n - 1)) ? 1 : 0;
  }
  __syncthreads();

  if (is_last) {
    double sm = 0.0;
    for (int bb = 0; bb < Bn; ++bb) {
      float p = (tid < Ln) ? mask[bb * Ln + tid] : 0.0f;
      #pragma unroll
      for (int o = 1; o < 64; o <<= 1) p += __shfl_xor(p, o, 64);
      __syncthreads();
      if ((tid & 63) == 0) red[tid >> 6] = p;
      __syncthreads();
      if (tid == 0) {
        float rs = 0.0f;
        #pragma unroll
        for (int i = 0; i < 8; ++i) rs += red[i];
        sm += (double)rs * (double)rs;
      }
    }
    __syncthreads();
    if (tid == 0) {
      const double a0 = atomicAdd(&acc[0], 0.0);
      const double a1 = atomicAdd(&acc[1], 0.0);
      const double a2 = atomicAdd(&acc[2], 0.0);
      const double lp = a0 / ((double)NHn * sm);
      const double lt = a1 / a2;
      out[0] = (float)(lp + lt);
    }
  }
}

// ---------------------------------------------------------------------------
extern "C" void kernel_launch(void* const* d_in, const int* in_sizes, int n_in,
                              void* d_out, int out_size, void* d_ws, size_t ws_size,
                              hipStream_t stream) {
  const float* s_rep = (const float*)d_in[0];
  const float* t_rep = (const float*)d_in[1];
  const float* mask  = (const float*)d_in[2];
  float* out = (float*)d_out;

  char* w = (char*)d_ws;
  double* acc      = (double*)(w + WS_ACC);
  unsigned int* done_cnt = (unsigned int*)(w + WS_ACC + 48);
  float* g_score   = (float*)(w + WS_GSCORE);
  int* g_top       = (int*)(w + WS_GTOP);
  float* loc_part  = (float*)(w + WS_LOCP);
  unsigned short* sbf = (unsigned short*)(w + WS_SBF);
  unsigned short* tbf = (unsigned short*)(w + WS_TBF);

  prep_bf16_kernel<<<Bn * Ln * Dn / 4 / 256, 256, 0, stream>>>(
      s_rep, t_rep, sbf, tbf, g_score, (int*)(w + WS_ACC));
  pairA_kernel<<<Bn * NHn * (Ln / 64), 256, 0, stream>>>(sbf, tbf, mask, g_score, acc);
  pairB_kernel<<<Bn * NHn, 256, 0, stream>>>(tbf, mask, g_score, g_top, loc_part);
  triplet_kernel<<<Bn * K1n, 512, 0, stream>>>(s_rep, t_rep, mask, g_top, loc_part,
                                               acc, done_cnt, out);
}